// Round 1
// baseline (1039.023 us; speedup 1.0000x reference)
//
#include <hip/hip_runtime.h>
#include <hip/hip_bf16.h>
#include <math.h>

#define TOK 8192
#define HD 768
#define ID 2048
#define NE 8
#define MSIZE (2048*768)
#define BM 128
#define BK 64
#define R_SHARED 8192
#define R_MAX 25600   // 8192 shared + 16384 routed + 8*128 max padding, = 200*128

typedef int v4i __attribute__((ext_vector_type(4)));
typedef __attribute__((address_space(1))) void gas_void;
typedef __attribute__((address_space(3))) void las_void;

__device__ __forceinline__ void g2lds16(const void* g, void* l) {
  __builtin_amdgcn_global_load_lds((gas_void*)g, (las_void*)l, 16, 0, 0);
}

__device__ __forceinline__ float clipf(float v, float lo, float hi) {
  return fminf(fmaxf(v, lo), hi);
}

__device__ __forceinline__ const float* matsel(int mat, const float* Wg, const float* Wu,
                                               const float* Wd, const float* sWg,
                                               const float* sWu, const float* sWd) {
  if (mat < 8)  return Wg + (size_t)mat * MSIZE;
  if (mat < 16) return Wu + (size_t)(mat - 8) * MSIZE;
  if (mat < 24) return Wd + (size_t)(mat - 16) * MSIZE;
  if (mat == 24) return sWg;
  if (mat == 25) return sWu;
  return sWd;
}

// ---------------- weight quantization ----------------
__global__ __launch_bounds__(256)
void k_wstats(const float* __restrict__ Wg, const float* __restrict__ Wu,
              const float* __restrict__ Wd, const float* __restrict__ sWg,
              const float* __restrict__ sWu, const float* __restrict__ sWd,
              double* __restrict__ stats) {
  int mat = blockIdx.y;
  const float* p = matsel(mat, Wg, Wu, Wd, sWg, sWu, sWd);
  int tid = threadIdx.x;
  double s = 0.0, sa = 0.0;
  for (size_t i = (size_t)blockIdx.x * 256 + tid; i < (size_t)MSIZE;
       i += (size_t)gridDim.x * 256) {
    double v = (double)p[i];
    s += v; sa += fabs(v);
  }
  __shared__ double rs[256], ra[256];
  rs[tid] = s; ra[tid] = sa; __syncthreads();
  for (int st = 128; st > 0; st >>= 1) {
    if (tid < st) { rs[tid] += rs[tid + st]; ra[tid] += ra[tid + st]; }
    __syncthreads();
  }
  if (tid == 0) {
    atomicAdd(&stats[mat * 2 + 0], rs[0]);
    atomicAdd(&stats[mat * 2 + 1], ra[0]);
  }
}

__global__ void k_wfinal(const double* __restrict__ stats, double* __restrict__ wmean,
                         float* __restrict__ wscale) {
  int m = threadIdx.x;
  if (m < 27) {
    wmean[m] = stats[m * 2] / (double)MSIZE;
    double sc = stats[m * 2 + 1] / (double)MSIZE;
    wscale[m] = (float)fmax(sc, 1e-8);
  }
}

__global__ __launch_bounds__(256)
void k_wquant(const float* __restrict__ Wg, const float* __restrict__ Wu,
              const float* __restrict__ Wd, const float* __restrict__ sWg,
              const float* __restrict__ sWu, const float* __restrict__ sWd,
              const double* __restrict__ wmean, signed char* __restrict__ tw) {
  int mat = blockIdx.y;
  const float* p = matsel(mat, Wg, Wu, Wd, sWg, sWu, sWd);
  const float4* p4 = (const float4*)p;
  int* t4 = (int*)(tw + (size_t)mat * MSIZE);
  double mu = wmean[mat];
  for (int i = blockIdx.x * 256 + threadIdx.x; i < MSIZE / 4; i += gridDim.x * 256) {
    float4 v = p4[i];
    int b0 = ((double)v.x > mu) ? 1 : (((double)v.x < mu) ? -1 : 0);
    int b1 = ((double)v.y > mu) ? 1 : (((double)v.y < mu) ? -1 : 0);
    int b2 = ((double)v.z > mu) ? 1 : (((double)v.z < mu) ? -1 : 0);
    int b3 = ((double)v.w > mu) ? 1 : (((double)v.w < mu) ? -1 : 0);
    t4[i] = (b0 & 255) | ((b1 & 255) << 8) | ((b2 & 255) << 16) | ((b3 & 255) << 24);
  }
}

// ---------------- router ----------------
__global__ __launch_bounds__(64)
void k_router(const float* __restrict__ x, const float* __restrict__ rw,
              const float* __restrict__ rb, float* __restrict__ logits,
              int* __restrict__ top_idx, float* __restrict__ top_w,
              int* __restrict__ counts) {
  int t = blockIdx.x, ln = threadIdx.x;
  float acc[NE] = {};
  const float* xr = x + (size_t)t * HD;
  for (int h = ln; h < HD; h += 64) {
    float xv = xr[h];
#pragma unroll
    for (int e = 0; e < NE; ++e) acc[e] += xv * rw[e * HD + h];
  }
#pragma unroll
  for (int e = 0; e < NE; ++e) {
    float v = acc[e];
#pragma unroll
    for (int o = 32; o > 0; o >>= 1) v += __shfl_down(v, o, 64);
    acc[e] = v;
  }
  if (ln == 0) {
    float lg[NE], m = -1e30f;
#pragma unroll
    for (int e = 0; e < NE; ++e) {
      lg[e] = acc[e] + rb[e];
      logits[(size_t)t * NE + e] = lg[e];
      m = fmaxf(m, lg[e]);
    }
    float p[NE], s = 0.f;
#pragma unroll
    for (int e = 0; e < NE; ++e) { p[e] = expf(lg[e] - m); s += p[e]; }
    float inv = 1.f / s;
#pragma unroll
    for (int e = 0; e < NE; ++e) p[e] *= inv;
    int e1 = 0; float b1 = p[0];
    for (int e = 1; e < NE; ++e) if (p[e] > b1) { b1 = p[e]; e1 = e; }
    int e2 = -1; float b2 = -1.f;
    for (int e = 0; e < NE; ++e) if (e != e1 && p[e] > b2) { b2 = p[e]; e2 = e; }
    float sw = b1 + b2 + 1e-8f;
    top_idx[t * 2 + 0] = e1; top_idx[t * 2 + 1] = e2;
    top_w[t * 2 + 0] = b1 / sw; top_w[t * 2 + 1] = b2 / sw;
    atomicAdd(&counts[e1], 1); atomicAdd(&counts[e2], 1);
  }
}

__global__ void k_initrows(int* __restrict__ rows_token, float* __restrict__ rows_w,
                           int* __restrict__ rows_expert) {
  int r = blockIdx.x * blockDim.x + threadIdx.x;
  if (r >= R_MAX) return;
  if (r < R_SHARED) { rows_token[r] = r; rows_w[r] = 1.f; rows_expert[r] = NE; }
  else { rows_token[r] = -1; rows_w[r] = 0.f; rows_expert[r] = 0; }
}

__global__ void k_offsets(const int* __restrict__ counts, int* __restrict__ offs,
                          int* __restrict__ fill) {
  if (threadIdx.x == 0) {
    int off = R_SHARED;
    for (int e = 0; e < NE; ++e) {
      offs[e] = off;
      off += ((counts[e] + BM - 1) / BM) * BM;
    }
    offs[NE] = off;
  }
  if (threadIdx.x < NE) fill[threadIdx.x] = 0;
}

__global__ void k_scatter(const int* __restrict__ top_idx, const float* __restrict__ top_w,
                          const int* __restrict__ offs, int* __restrict__ fill,
                          int* __restrict__ rows_token, float* __restrict__ rows_w,
                          int* __restrict__ rows_expert) {
  int t = blockIdx.x * blockDim.x + threadIdx.x;
  if (t >= TOK) return;
#pragma unroll
  for (int k = 0; k < 2; ++k) {
    int e = top_idx[t * 2 + k];
    int pos = atomicAdd(&fill[e], 1);
    int r = offs[e] + pos;
    rows_token[r] = t;
    rows_w[r] = top_w[t * 2 + k];
    rows_expert[r] = e;
  }
}

// ---------------- activation quant (x -> xq_g, xq_u) ----------------
__global__ __launch_bounds__(256)
void k_actquant(const float* __restrict__ x, const int* __restrict__ rows_token,
                const int* __restrict__ rows_expert, const float* __restrict__ ng,
                const float* __restrict__ nu, const float* __restrict__ sng,
                const float* __restrict__ snu, signed char* __restrict__ xqg,
                signed char* __restrict__ xqu, float* __restrict__ invg,
                float* __restrict__ invu) {
  int r = blockIdx.x, tid = threadIdx.x;
  int tok = rows_token[r];
  if (tok < 0) {
    for (int i = tid; i < HD; i += 256) {
      xqg[(size_t)r * HD + i] = 0; xqu[(size_t)r * HD + i] = 0;
    }
    if (tid == 0) { invg[r] = 0.f; invu[r] = 0.f; }
    return;
  }
  int e = rows_expert[r];
  const float* wg = (e < NE) ? ng + (size_t)e * HD : sng;
  const float* wu = (e < NE) ? nu + (size_t)e * HD : snu;
  __shared__ float red[256];
  float xv[3]; float ss = 0.f;
#pragma unroll
  for (int i = 0; i < 3; ++i) {
    float v = x[(size_t)tok * HD + tid + i * 256];
    v = clipf(v, -100.f, 100.f);
    xv[i] = v; ss += v * v;
  }
  red[tid] = ss; __syncthreads();
  for (int st = 128; st > 0; st >>= 1) { if (tid < st) red[tid] += red[tid + st]; __syncthreads(); }
  float var = fmaxf(red[0] / (float)HD, 1e-5f);
  __syncthreads();
  float rinv = rsqrtf(var + 1e-5f);
  // gate path
  float xn[3]; float amax = 0.f;
#pragma unroll
  for (int i = 0; i < 3; ++i) {
    float t = clipf(xv[i] * rinv, -10.f, 10.f) * wg[tid + i * 256];
    t = clipf(t, -50.f, 50.f);
    xn[i] = t; amax = fmaxf(amax, fabsf(t));
  }
  red[tid] = amax; __syncthreads();
  for (int st = 128; st > 0; st >>= 1) { if (tid < st) red[tid] = fmaxf(red[tid], red[tid + st]); __syncthreads(); }
  float mx = fmaxf(red[0], 1e-4f);
  __syncthreads();
  float sc = 127.f / mx;
#pragma unroll
  for (int i = 0; i < 3; ++i)
    xqg[(size_t)r * HD + tid + i * 256] = (signed char)(int)clipf(rintf(xn[i] * sc), -128.f, 127.f);
  if (tid == 0) invg[r] = 1.f / sc;
  // up path
  amax = 0.f;
#pragma unroll
  for (int i = 0; i < 3; ++i) {
    float t = clipf(xv[i] * rinv, -10.f, 10.f) * wu[tid + i * 256];
    t = clipf(t, -50.f, 50.f);
    xn[i] = t; amax = fmaxf(amax, fabsf(t));
  }
  red[tid] = amax; __syncthreads();
  for (int st = 128; st > 0; st >>= 1) { if (tid < st) red[tid] = fmaxf(red[tid], red[tid + st]); __syncthreads(); }
  mx = fmaxf(red[0], 1e-4f);
  __syncthreads();
  sc = 127.f / mx;
#pragma unroll
  for (int i = 0; i < 3; ++i)
    xqu[(size_t)r * HD + tid + i * 256] = (signed char)(int)clipf(rintf(xn[i] * sc), -128.f, 127.f);
  if (tid == 0) invu[r] = 1.f / sc;
}

// ---------------- fused gate+up int8 GEMM -> hidden (bf16) ----------------
__global__ __launch_bounds__(256, 1)
void k_gemm_gu(const signed char* __restrict__ xqg, const signed char* __restrict__ xqu,
               const signed char* __restrict__ tw, const float* __restrict__ wscale,
               const float* __restrict__ invg, const float* __restrict__ invu,
               const int* __restrict__ rows_expert, const int* __restrict__ offs,
               __hip_bfloat16* __restrict__ hidden) {
  int row0 = blockIdx.x * BM;
  if (row0 >= offs[NE]) return;
  int n0 = blockIdx.y * BM;
  int e = rows_expert[row0];
  int mg = (e < NE) ? e : 24;
  int mu = (e < NE) ? e + 8 : 25;
  const signed char* wgp = tw + (size_t)mg * MSIZE;
  const signed char* wup = tw + (size_t)mu * MSIZE;
  __shared__ __align__(16) signed char Ag[BM * BK];
  __shared__ __align__(16) signed char Au[BM * BK];
  __shared__ __align__(16) signed char Bg[BM * BK];
  __shared__ __align__(16) signed char Bu[BM * BK];
  __shared__ float sg[BM], su[BM];
  int tid = threadIdx.x, wv = tid >> 6, ln = tid & 63;
  if (tid < BM) { sg[tid] = invg[row0 + tid]; su[tid] = invu[row0 + tid]; }
  v4i accg[4][4] = {};
  v4i accu[4][4] = {};
  int lr = ln >> 2, lc = (ln & 3) * 16;
  int wm = (wv & 1) * 64, wn = (wv >> 1) * 64;
  int fm = ln & 15, fk = (ln >> 4) * 16;
  for (int kk = 0; kk < HD; kk += BK) {
#pragma unroll
    for (int j = 0; j < 2; ++j) {
      int chunk = wv * 2 + j;
      int row = chunk * 16 + lr;
      size_t aoff = (size_t)(row0 + row) * HD + kk + lc;
      size_t boff = (size_t)(n0 + row) * HD + kk + lc;
      g2lds16(xqg + aoff, &Ag[chunk * 1024]);
      g2lds16(xqu + aoff, &Au[chunk * 1024]);
      g2lds16(wgp + boff, &Bg[chunk * 1024]);
      g2lds16(wup + boff, &Bu[chunk * 1024]);
    }
    __syncthreads();
    v4i ag[4], au[4];
#pragma unroll
    for (int i = 0; i < 4; ++i) {
      ag[i] = *(const v4i*)&Ag[(wm + i * 16 + fm) * BK + fk];
      au[i] = *(const v4i*)&Au[(wm + i * 16 + fm) * BK + fk];
    }
#pragma unroll
    for (int j = 0; j < 4; ++j) {
      v4i bg = *(const v4i*)&Bg[(wn + j * 16 + fm) * BK + fk];
      v4i bu = *(const v4i*)&Bu[(wn + j * 16 + fm) * BK + fk];
#pragma unroll
      for (int i = 0; i < 4; ++i) {
        accg[i][j] = __builtin_amdgcn_mfma_i32_16x16x64_i8(ag[i], bg, accg[i][j], 0, 0, 0);
        accu[i][j] = __builtin_amdgcn_mfma_i32_16x16x64_i8(au[i], bu, accu[i][j], 0, 0, 0);
      }
    }
    __syncthreads();
  }
  float gs = wscale[mg], us = wscale[mu];
  int dq = (ln >> 4) * 4, dn = ln & 15;
  for (int i = 0; i < 4; ++i) {
#pragma unroll
    for (int rg = 0; rg < 4; ++rg) {
      int lrow = wm + i * 16 + dq + rg;
      int grow = row0 + lrow;
      float ig = gs * sg[lrow];
      float iu = us * su[lrow];
#pragma unroll
      for (int j = 0; j < 4; ++j) {
        int gcol = n0 + wn + j * 16 + dn;
        float g = (float)accg[i][j][rg] * ig;
        g = clipf(g, -20.f, 20.f);
        float sil = g / (1.f + expf(-g));
        float u = (float)accu[i][j][rg] * iu;
        float h = clipf(sil * u, -1000.f, 1000.f);
        hidden[(size_t)grow * ID + gcol] = __float2bfloat16(h);
      }
    }
  }
}

// ---------------- hidden quant ----------------
__global__ __launch_bounds__(256)
void k_hquant(const __hip_bfloat16* __restrict__ hidden, const int* __restrict__ rows_token,
              const int* __restrict__ rows_expert, const float* __restrict__ nd,
              const float* __restrict__ snd, signed char* __restrict__ hq,
              float* __restrict__ invh) {
  int r = blockIdx.x, tid = threadIdx.x;
  int tok = rows_token[r];
  if (tok < 0) {
    for (int i = tid; i < ID; i += 256) hq[(size_t)r * ID + i] = 0;
    if (tid == 0) invh[r] = 0.f;
    return;
  }
  int e = rows_expert[r];
  const float* wn = (e < NE) ? nd + (size_t)e * ID : snd;
  __shared__ float red[256];
  float xv[8]; float ss = 0.f;
#pragma unroll
  for (int i = 0; i < 8; ++i) {
    float v = __bfloat162float(hidden[(size_t)r * ID + tid + i * 256]);
    v = clipf(v, -100.f, 100.f);
    xv[i] = v; ss += v * v;
  }
  red[tid] = ss; __syncthreads();
  for (int st = 128; st > 0; st >>= 1) { if (tid < st) red[tid] += red[tid + st]; __syncthreads(); }
  float var = fmaxf(red[0] / (float)ID, 1e-5f);
  __syncthreads();
  float rinv = rsqrtf(var + 1e-5f);
  float xn[8]; float amax = 0.f;
#pragma unroll
  for (int i = 0; i < 8; ++i) {
    float t = clipf(xv[i] * rinv, -10.f, 10.f) * wn[tid + i * 256];
    t = clipf(t, -50.f, 50.f);
    xn[i] = t; amax = fmaxf(amax, fabsf(t));
  }
  red[tid] = amax; __syncthreads();
  for (int st = 128; st > 0; st >>= 1) { if (tid < st) red[tid] = fmaxf(red[tid], red[tid + st]); __syncthreads(); }
  float mx = fmaxf(red[0], 1e-4f);
  __syncthreads();
  float sc = 127.f / mx;
#pragma unroll
  for (int i = 0; i < 8; ++i)
    hq[(size_t)r * ID + tid + i * 256] = (signed char)(int)clipf(rintf(xn[i] * sc), -128.f, 127.f);
  if (tid == 0) invh[r] = 1.f / sc;
}

// ---------------- down int8 GEMM + weighted scatter-add ----------------
__global__ __launch_bounds__(256, 1)
void k_gemm_down(const signed char* __restrict__ hq, const signed char* __restrict__ tw,
                 const float* __restrict__ wscale, const float* __restrict__ invh,
                 const int* __restrict__ rows_token, const float* __restrict__ rows_w,
                 const int* __restrict__ rows_expert, const int* __restrict__ offs,
                 float* __restrict__ out) {
  int row0 = blockIdx.x * BM;
  if (row0 >= offs[NE]) return;
  int n0 = blockIdx.y * BM;
  int e = rows_expert[row0];
  int md = (e < NE) ? 16 + e : 26;
  const signed char* wdp = tw + (size_t)md * MSIZE;
  __shared__ __align__(16) signed char As[BM * BK];
  __shared__ __align__(16) signed char Bs[BM * BK];
  __shared__ float s_f[BM];
  __shared__ int s_tok[BM];
  int tid = threadIdx.x, wv = tid >> 6, ln = tid & 63;
  if (tid < BM) {
    s_f[tid] = invh[row0 + tid] * rows_w[row0 + tid];
    s_tok[tid] = rows_token[row0 + tid];
  }
  v4i acc[4][4] = {};
  int lr = ln >> 2, lc = (ln & 3) * 16;
  int wm = (wv & 1) * 64, wn = (wv >> 1) * 64;
  int fm = ln & 15, fk = (ln >> 4) * 16;
  for (int kk = 0; kk < ID; kk += BK) {
#pragma unroll
    for (int j = 0; j < 2; ++j) {
      int chunk = wv * 2 + j;
      int row = chunk * 16 + lr;
      g2lds16(hq + (size_t)(row0 + row) * ID + kk + lc, &As[chunk * 1024]);
      g2lds16(wdp + (size_t)(n0 + row) * ID + kk + lc, &Bs[chunk * 1024]);
    }
    __syncthreads();
    v4i a[4];
#pragma unroll
    for (int i = 0; i < 4; ++i) a[i] = *(const v4i*)&As[(wm + i * 16 + fm) * BK + fk];
#pragma unroll
    for (int j = 0; j < 4; ++j) {
      v4i b = *(const v4i*)&Bs[(wn + j * 16 + fm) * BK + fk];
#pragma unroll
      for (int i = 0; i < 4; ++i)
        acc[i][j] = __builtin_amdgcn_mfma_i32_16x16x64_i8(a[i], b, acc[i][j], 0, 0, 0);
    }
    __syncthreads();
  }
  float ds = wscale[md];
  int dq = (ln >> 4) * 4, dn = ln & 15;
  for (int i = 0; i < 4; ++i) {
#pragma unroll
    for (int rg = 0; rg < 4; ++rg) {
      int lrow = wm + i * 16 + dq + rg;
      int tok = s_tok[lrow];
      if (tok < 0) continue;
      float f = ds * s_f[lrow];
#pragma unroll
      for (int j = 0; j < 4; ++j) {
        int gcol = n0 + wn + j * 16 + dn;
        atomicAdd(&out[(size_t)tok * HD + gcol], (float)acc[i][j][rg] * f);
      }
    }
  }
}

__global__ void k_clip(float* __restrict__ out, int n) {
  for (int i = blockIdx.x * blockDim.x + threadIdx.x; i < n; i += gridDim.x * blockDim.x)
    out[i] = clipf(out[i], -10000.f, 10000.f);
}

// ---------------- host launcher ----------------
extern "C" void kernel_launch(void* const* d_in, const int* in_sizes, int n_in,
                              void* d_out, int out_size, void* d_ws, size_t ws_size,
                              hipStream_t stream) {
  (void)in_sizes; (void)n_in; (void)out_size; (void)ws_size;
  const float* x   = (const float*)d_in[0];
  const float* rw  = (const float*)d_in[1];
  const float* rb  = (const float*)d_in[2];
  const float* Wg  = (const float*)d_in[3];
  const float* Wu  = (const float*)d_in[4];
  const float* Wd  = (const float*)d_in[5];
  const float* ng  = (const float*)d_in[6];
  const float* nu  = (const float*)d_in[7];
  const float* nd  = (const float*)d_in[8];
  const float* sWg = (const float*)d_in[9];
  const float* sWu = (const float*)d_in[10];
  const float* sWd = (const float*)d_in[11];
  const float* sng = (const float*)d_in[12];
  const float* snu = (const float*)d_in[13];
  const float* snd = (const float*)d_in[14];
  float* out = (float*)d_out;
  float* logits = out + (size_t)TOK * HD;

  char* ws = (char*)d_ws;
  size_t off = 0;
  auto alloc = [&](size_t b) { size_t o = off; off = (off + b + 255) & ~(size_t)255; return o; };
  signed char* tw   = (signed char*)(ws + alloc((size_t)27 * MSIZE));
  double* stats     = (double*)(ws + alloc(27 * 2 * sizeof(double)));
  double* wmean     = (double*)(ws + alloc(27 * sizeof(double)));
  float* wscale     = (float*)(ws + alloc(27 * sizeof(float)));
  int* counts       = (int*)(ws + alloc(8 * sizeof(int)));
  int* fill         = (int*)(ws + alloc(8 * sizeof(int)));
  int* offs         = (int*)(ws + alloc(16 * sizeof(int)));
  int* top_idx      = (int*)(ws + alloc((size_t)TOK * 2 * sizeof(int)));
  float* top_w      = (float*)(ws + alloc((size_t)TOK * 2 * sizeof(float)));
  int* rows_token   = (int*)(ws + alloc((size_t)R_MAX * sizeof(int)));
  float* rows_w     = (float*)(ws + alloc((size_t)R_MAX * sizeof(float)));
  int* rows_expert  = (int*)(ws + alloc((size_t)R_MAX * sizeof(int)));
  float* invg       = (float*)(ws + alloc((size_t)R_MAX * sizeof(float)));
  float* invu       = (float*)(ws + alloc((size_t)R_MAX * sizeof(float)));
  float* invh       = (float*)(ws + alloc((size_t)R_MAX * sizeof(float)));
  // hq region; xqg/xqu alias its front (safe: xq consumed by k_gemm_gu before k_hquant writes hq)
  signed char* hq   = (signed char*)(ws + alloc((size_t)R_MAX * ID));
  signed char* xqg  = hq;
  signed char* xqu  = hq + (size_t)R_MAX * HD;
  __hip_bfloat16* hidden = (__hip_bfloat16*)(ws + alloc((size_t)R_MAX * ID * 2));

  hipMemsetAsync(stats, 0, 27 * 2 * sizeof(double), stream);
  hipMemsetAsync(counts, 0, 8 * sizeof(int), stream);
  hipMemsetAsync(out, 0, (size_t)TOK * HD * sizeof(float), stream);

  k_wstats<<<dim3(64, 27), 256, 0, stream>>>(Wg, Wu, Wd, sWg, sWu, sWd, stats);
  k_wfinal<<<1, 32, 0, stream>>>(stats, wmean, wscale);
  k_wquant<<<dim3(256, 27), 256, 0, stream>>>(Wg, Wu, Wd, sWg, sWu, sWd, wmean, tw);
  k_router<<<TOK, 64, 0, stream>>>(x, rw, rb, logits, top_idx, top_w, counts);
  k_initrows<<<(R_MAX + 255) / 256, 256, 0, stream>>>(rows_token, rows_w, rows_expert);
  k_offsets<<<1, 64, 0, stream>>>(counts, offs, fill);
  k_scatter<<<TOK / 256, 256, 0, stream>>>(top_idx, top_w, offs, fill, rows_token, rows_w, rows_expert);
  k_actquant<<<R_MAX, 256, 0, stream>>>(x, rows_token, rows_expert, ng, nu, sng, snu,
                                        xqg, xqu, invg, invu);
  k_gemm_gu<<<dim3(R_MAX / BM, ID / BM), 256, 0, stream>>>(xqg, xqu, tw, wscale, invg, invu,
                                                           rows_expert, offs, hidden);
  k_hquant<<<R_MAX, 256, 0, stream>>>(hidden, rows_token, rows_expert, nd, snd, hq, invh);
  k_gemm_down<<<dim3(R_MAX / BM, HD / BM), 256, 0, stream>>>(hq, tw, wscale, invh, rows_token,
                                                             rows_w, rows_expert, offs, out);
  k_clip<<<4096, 256, 0, stream>>>(out, TOK * HD);
}

// Round 2
// 915.931 us; speedup vs baseline: 1.1344x; 1.1344x over previous
//
#include <hip/hip_runtime.h>
#include <hip/hip_bf16.h>
#include <math.h>

#define TOK 8192
#define HD 768
#define ID 2048
#define NE 8
#define MSIZE (2048*768)
#define BM 128
#define BK 64
#define R_SHARED 8192
#define R_MAX 25600   // 8192 shared + 16384 routed + 8*128 max padding, = 200*128

typedef int v4i __attribute__((ext_vector_type(4)));
typedef __attribute__((address_space(1))) void gas_void;
typedef __attribute__((address_space(3))) void las_void;

__device__ __forceinline__ void g2lds16(const void* g, void* l) {
  __builtin_amdgcn_global_load_lds((gas_void*)g, (las_void*)l, 16, 0, 0);
}

__device__ __forceinline__ float clipf(float v, float lo, float hi) {
  return fminf(fmaxf(v, lo), hi);
}

__device__ __forceinline__ const float* matsel(int mat, const float* Wg, const float* Wu,
                                               const float* Wd, const float* sWg,
                                               const float* sWu, const float* sWd) {
  if (mat < 8)  return Wg + (size_t)mat * MSIZE;
  if (mat < 16) return Wu + (size_t)(mat - 8) * MSIZE;
  if (mat < 24) return Wd + (size_t)(mat - 16) * MSIZE;
  if (mat == 24) return sWg;
  if (mat == 25) return sWu;
  return sWd;
}

// ---------------- weight quantization ----------------
__global__ __launch_bounds__(256)
void k_wstats(const float* __restrict__ Wg, const float* __restrict__ Wu,
              const float* __restrict__ Wd, const float* __restrict__ sWg,
              const float* __restrict__ sWu, const float* __restrict__ sWd,
              double* __restrict__ stats) {
  int mat = blockIdx.y;
  const float* p = matsel(mat, Wg, Wu, Wd, sWg, sWu, sWd);
  int tid = threadIdx.x;
  double s = 0.0, sa = 0.0;
  for (size_t i = (size_t)blockIdx.x * 256 + tid; i < (size_t)MSIZE;
       i += (size_t)gridDim.x * 256) {
    double v = (double)p[i];
    s += v; sa += fabs(v);
  }
  __shared__ double rs[256], ra[256];
  rs[tid] = s; ra[tid] = sa; __syncthreads();
  for (int st = 128; st > 0; st >>= 1) {
    if (tid < st) { rs[tid] += rs[tid + st]; ra[tid] += ra[tid + st]; }
    __syncthreads();
  }
  if (tid == 0) {
    atomicAdd(&stats[mat * 2 + 0], rs[0]);
    atomicAdd(&stats[mat * 2 + 1], ra[0]);
  }
}

__global__ void k_wfinal(const double* __restrict__ stats, double* __restrict__ wmean,
                         float* __restrict__ wscale) {
  int m = threadIdx.x;
  if (m < 27) {
    wmean[m] = stats[m * 2] / (double)MSIZE;
    double sc = stats[m * 2 + 1] / (double)MSIZE;
    wscale[m] = (float)fmax(sc, 1e-8);
  }
}

__global__ __launch_bounds__(256)
void k_wquant(const float* __restrict__ Wg, const float* __restrict__ Wu,
              const float* __restrict__ Wd, const float* __restrict__ sWg,
              const float* __restrict__ sWu, const float* __restrict__ sWd,
              const double* __restrict__ wmean, signed char* __restrict__ tw) {
  int mat = blockIdx.y;
  const float* p = matsel(mat, Wg, Wu, Wd, sWg, sWu, sWd);
  const float4* p4 = (const float4*)p;
  int* t4 = (int*)(tw + (size_t)mat * MSIZE);
  double mu = wmean[mat];
  for (int i = blockIdx.x * 256 + threadIdx.x; i < MSIZE / 4; i += gridDim.x * 256) {
    float4 v = p4[i];
    int b0 = ((double)v.x > mu) ? 1 : (((double)v.x < mu) ? -1 : 0);
    int b1 = ((double)v.y > mu) ? 1 : (((double)v.y < mu) ? -1 : 0);
    int b2 = ((double)v.z > mu) ? 1 : (((double)v.z < mu) ? -1 : 0);
    int b3 = ((double)v.w > mu) ? 1 : (((double)v.w < mu) ? -1 : 0);
    t4[i] = (b0 & 255) | ((b1 & 255) << 8) | ((b2 & 255) << 16) | ((b3 & 255) << 24);
  }
}

// ---------------- router ----------------
__global__ __launch_bounds__(64)
void k_router(const float* __restrict__ x, const float* __restrict__ rw,
              const float* __restrict__ rb, float* __restrict__ logits,
              int* __restrict__ top_idx, float* __restrict__ top_w,
              int* __restrict__ counts) {
  int t = blockIdx.x, ln = threadIdx.x;
  float acc[NE] = {};
  const float* xr = x + (size_t)t * HD;
  for (int h = ln; h < HD; h += 64) {
    float xv = xr[h];
#pragma unroll
    for (int e = 0; e < NE; ++e) acc[e] += xv * rw[e * HD + h];
  }
#pragma unroll
  for (int e = 0; e < NE; ++e) {
    float v = acc[e];
#pragma unroll
    for (int o = 32; o > 0; o >>= 1) v += __shfl_down(v, o, 64);
    acc[e] = v;
  }
  if (ln == 0) {
    float lg[NE], m = -1e30f;
#pragma unroll
    for (int e = 0; e < NE; ++e) {
      lg[e] = acc[e] + rb[e];
      logits[(size_t)t * NE + e] = lg[e];
      m = fmaxf(m, lg[e]);
    }
    float p[NE], s = 0.f;
#pragma unroll
    for (int e = 0; e < NE; ++e) { p[e] = expf(lg[e] - m); s += p[e]; }
    float inv = 1.f / s;
#pragma unroll
    for (int e = 0; e < NE; ++e) p[e] *= inv;
    int e1 = 0; float b1 = p[0];
    for (int e = 1; e < NE; ++e) if (p[e] > b1) { b1 = p[e]; e1 = e; }
    int e2 = -1; float b2 = -1.f;
    for (int e = 0; e < NE; ++e) if (e != e1 && p[e] > b2) { b2 = p[e]; e2 = e; }
    float sw = b1 + b2 + 1e-8f;
    top_idx[t * 2 + 0] = e1; top_idx[t * 2 + 1] = e2;
    top_w[t * 2 + 0] = b1 / sw; top_w[t * 2 + 1] = b2 / sw;
    atomicAdd(&counts[e1], 1); atomicAdd(&counts[e2], 1);
  }
}

__global__ void k_initrows(int* __restrict__ rows_token, float* __restrict__ rows_w,
                           int* __restrict__ rows_expert) {
  int r = blockIdx.x * blockDim.x + threadIdx.x;
  if (r >= R_MAX) return;
  if (r < R_SHARED) { rows_token[r] = r; rows_w[r] = 1.f; rows_expert[r] = NE; }
  else { rows_token[r] = -1; rows_w[r] = 0.f; rows_expert[r] = 0; }
}

__global__ void k_offsets(const int* __restrict__ counts, int* __restrict__ offs,
                          int* __restrict__ fill) {
  if (threadIdx.x == 0) {
    int off = R_SHARED;
    for (int e = 0; e < NE; ++e) {
      offs[e] = off;
      off += ((counts[e] + BM - 1) / BM) * BM;
    }
    offs[NE] = off;
  }
  if (threadIdx.x < NE) fill[threadIdx.x] = 0;
}

__global__ void k_scatter(const int* __restrict__ top_idx, const float* __restrict__ top_w,
                          const int* __restrict__ offs, int* __restrict__ fill,
                          int* __restrict__ rows_token, float* __restrict__ rows_w,
                          int* __restrict__ rows_expert) {
  int t = blockIdx.x * blockDim.x + threadIdx.x;
  if (t >= TOK) return;
#pragma unroll
  for (int k = 0; k < 2; ++k) {
    int e = top_idx[t * 2 + k];
    int pos = atomicAdd(&fill[e], 1);
    int r = offs[e] + pos;
    rows_token[r] = t;
    rows_w[r] = top_w[t * 2 + k];
    rows_expert[r] = e;
  }
}

// ---------------- activation quant (x -> xq_g, xq_u) ----------------
__global__ __launch_bounds__(256)
void k_actquant(const float* __restrict__ x, const int* __restrict__ rows_token,
                const int* __restrict__ rows_expert, const float* __restrict__ ng,
                const float* __restrict__ nu, const float* __restrict__ sng,
                const float* __restrict__ snu, signed char* __restrict__ xqg,
                signed char* __restrict__ xqu, float* __restrict__ invg,
                float* __restrict__ invu) {
  int r = blockIdx.x, tid = threadIdx.x;
  int tok = rows_token[r];
  if (tok < 0) {
    for (int i = tid; i < HD; i += 256) {
      xqg[(size_t)r * HD + i] = 0; xqu[(size_t)r * HD + i] = 0;
    }
    if (tid == 0) { invg[r] = 0.f; invu[r] = 0.f; }
    return;
  }
  int e = rows_expert[r];
  const float* wg = (e < NE) ? ng + (size_t)e * HD : sng;
  const float* wu = (e < NE) ? nu + (size_t)e * HD : snu;
  __shared__ float red[256];
  float xv[3]; float ss = 0.f;
#pragma unroll
  for (int i = 0; i < 3; ++i) {
    float v = x[(size_t)tok * HD + tid + i * 256];
    v = clipf(v, -100.f, 100.f);
    xv[i] = v; ss += v * v;
  }
  red[tid] = ss; __syncthreads();
  for (int st = 128; st > 0; st >>= 1) { if (tid < st) red[tid] += red[tid + st]; __syncthreads(); }
  float var = fmaxf(red[0] / (float)HD, 1e-5f);
  __syncthreads();
  float rinv = rsqrtf(var + 1e-5f);
  // gate path
  float xn[3]; float amax = 0.f;
#pragma unroll
  for (int i = 0; i < 3; ++i) {
    float t = clipf(xv[i] * rinv, -10.f, 10.f) * wg[tid + i * 256];
    t = clipf(t, -50.f, 50.f);
    xn[i] = t; amax = fmaxf(amax, fabsf(t));
  }
  red[tid] = amax; __syncthreads();
  for (int st = 128; st > 0; st >>= 1) { if (tid < st) red[tid] = fmaxf(red[tid], red[tid + st]); __syncthreads(); }
  float mx = fmaxf(red[0], 1e-4f);
  __syncthreads();
  float sc = 127.f / mx;
#pragma unroll
  for (int i = 0; i < 3; ++i)
    xqg[(size_t)r * HD + tid + i * 256] = (signed char)(int)clipf(rintf(xn[i] * sc), -128.f, 127.f);
  if (tid == 0) invg[r] = 1.f / sc;
  // up path
  amax = 0.f;
#pragma unroll
  for (int i = 0; i < 3; ++i) {
    float t = clipf(xv[i] * rinv, -10.f, 10.f) * wu[tid + i * 256];
    t = clipf(t, -50.f, 50.f);
    xn[i] = t; amax = fmaxf(amax, fabsf(t));
  }
  red[tid] = amax; __syncthreads();
  for (int st = 128; st > 0; st >>= 1) { if (tid < st) red[tid] = fmaxf(red[tid], red[tid + st]); __syncthreads(); }
  mx = fmaxf(red[0], 1e-4f);
  __syncthreads();
  sc = 127.f / mx;
#pragma unroll
  for (int i = 0; i < 3; ++i)
    xqu[(size_t)r * HD + tid + i * 256] = (signed char)(int)clipf(rintf(xn[i] * sc), -128.f, 127.f);
  if (tid == 0) invu[r] = 1.f / sc;
}

// ---------------- fused gate+up int8 GEMM -> hidden (bf16) ----------------
// Double-buffered LDS (prefetch issued before compute so the barrier vmcnt-drain
// overlaps ~800 cyc of MFMA+LDS work), XOR-swizzled k-slots (kills the 8-way
// stride-64B bank conflicts; swizzle applied to the GLOBAL address since
// global_load_lds's LDS side is fixed lane-contiguous), grid transposed so
// consecutive blocks share the A row-tile (L2/L3 locality).
__global__ __launch_bounds__(256, 2)
void k_gemm_gu(const signed char* __restrict__ xqg, const signed char* __restrict__ xqu,
               const signed char* __restrict__ tw, const float* __restrict__ wscale,
               const float* __restrict__ invg, const float* __restrict__ invu,
               const int* __restrict__ rows_expert, const int* __restrict__ offs,
               __hip_bfloat16* __restrict__ hidden) {
  int n0 = blockIdx.x * BM;
  int row0 = blockIdx.y * BM;
  if (row0 >= offs[NE]) return;
  int e = rows_expert[row0];
  int mg = (e < NE) ? e : 24;
  int mu = (e < NE) ? e + 8 : 25;
  const signed char* wgp = tw + (size_t)mg * MSIZE;
  const signed char* wup = tw + (size_t)mu * MSIZE;
  __shared__ __align__(16) signed char Ag[2 * BM * BK];
  __shared__ __align__(16) signed char Au[2 * BM * BK];
  __shared__ __align__(16) signed char Bg[2 * BM * BK];
  __shared__ __align__(16) signed char Bu[2 * BM * BK];
  __shared__ float sg[BM], su[BM];
  int tid = threadIdx.x, wv = tid >> 6, ln = tid & 63;
  if (tid < BM) { sg[tid] = invg[row0 + tid]; su[tid] = invu[row0 + tid]; }
  v4i accg[4][4] = {};
  v4i accu[4][4] = {};
  // staging: lane ln covers row chunk*16 + (ln>>2), 16B slot (ln&3), with XOR swizzle
  int lr = ln >> 2;
  int swz = (((ln & 3) ^ ((lr >> 1) & 3)) << 4);
  const signed char* pag[2]; const signed char* pau[2];
  const signed char* pbg[2]; const signed char* pbu[2];
#pragma unroll
  for (int j = 0; j < 2; ++j) {
    int row = (wv * 2 + j) * 16 + lr;
    pag[j] = xqg + (size_t)(row0 + row) * HD + swz;
    pau[j] = xqu + (size_t)(row0 + row) * HD + swz;
    pbg[j] = wgp + (size_t)(n0 + row) * HD + swz;
    pbu[j] = wup + (size_t)(n0 + row) * HD + swz;
  }
  // fragment read offsets (loop-invariant): slot = kc ^ ((row>>1)&3); the row-
  // dependent part reduces to (fm>>1)&3 for all tiles in this wave.
  int wm = (wv & 1) * 64, wn = (wv >> 1) * 64;
  int fm = ln & 15;
  int slot16 = (((ln >> 4) ^ ((fm >> 1) & 3)) << 4);
  int offA[4], offB[4];
#pragma unroll
  for (int i = 0; i < 4; ++i) offA[i] = (wm + i * 16 + fm) * BK + slot16;
#pragma unroll
  for (int j = 0; j < 4; ++j) offB[j] = (wn + j * 16 + fm) * BK + slot16;

  auto stage = [&](int buf) {
#pragma unroll
    for (int j = 0; j < 2; ++j) {
      int co = buf * 8192 + (wv * 2 + j) * 1024;
      g2lds16(pag[j], &Ag[co]);
      g2lds16(pau[j], &Au[co]);
      g2lds16(pbg[j], &Bg[co]);
      g2lds16(pbu[j], &Bu[co]);
      pag[j] += BK; pau[j] += BK; pbg[j] += BK; pbu[j] += BK;
    }
  };
  auto compute = [&](int buf) {
    int lb = buf * 8192;
    v4i ag[4], au[4];
#pragma unroll
    for (int i = 0; i < 4; ++i) {
      ag[i] = *(const v4i*)&Ag[lb + offA[i]];
      au[i] = *(const v4i*)&Au[lb + offA[i]];
    }
#pragma unroll
    for (int j = 0; j < 4; ++j) {
      v4i bg = *(const v4i*)&Bg[lb + offB[j]];
      v4i bu = *(const v4i*)&Bu[lb + offB[j]];
#pragma unroll
      for (int i = 0; i < 4; ++i) {
        accg[i][j] = __builtin_amdgcn_mfma_i32_16x16x64_i8(ag[i], bg, accg[i][j], 0, 0, 0);
        accu[i][j] = __builtin_amdgcn_mfma_i32_16x16x64_i8(au[i], bu, accu[i][j], 0, 0, 0);
      }
    }
  };

  const int NIT = HD / BK;  // 12
  stage(0);
#pragma unroll 1
  for (int it = 0; it < NIT; it += 2) {
    __syncthreads();
    if (it + 1 < NIT) stage(1);
    compute(0);
    __syncthreads();
    if (it + 2 < NIT) stage(0);
    compute(1);
  }

  float gs = wscale[mg], us = wscale[mu];
  int dq = (ln >> 4) * 4, dn = ln & 15;
  for (int i = 0; i < 4; ++i) {
#pragma unroll
    for (int rg = 0; rg < 4; ++rg) {
      int lrow = wm + i * 16 + dq + rg;
      int grow = row0 + lrow;
      float ig = gs * sg[lrow];
      float iu = us * su[lrow];
#pragma unroll
      for (int j = 0; j < 4; ++j) {
        int gcol = n0 + wn + j * 16 + dn;
        float g = (float)accg[i][j][rg] * ig;
        g = clipf(g, -20.f, 20.f);
        float sil = g / (1.f + expf(-g));
        float u = (float)accu[i][j][rg] * iu;
        float h = clipf(sil * u, -1000.f, 1000.f);
        hidden[(size_t)grow * ID + gcol] = __float2bfloat16(h);
      }
    }
  }
}

// ---------------- hidden quant ----------------
__global__ __launch_bounds__(256)
void k_hquant(const __hip_bfloat16* __restrict__ hidden, const int* __restrict__ rows_token,
              const int* __restrict__ rows_expert, const float* __restrict__ nd,
              const float* __restrict__ snd, signed char* __restrict__ hq,
              float* __restrict__ invh) {
  int r = blockIdx.x, tid = threadIdx.x;
  int tok = rows_token[r];
  if (tok < 0) {
    for (int i = tid; i < ID; i += 256) hq[(size_t)r * ID + i] = 0;
    if (tid == 0) invh[r] = 0.f;
    return;
  }
  int e = rows_expert[r];
  const float* wn = (e < NE) ? nd + (size_t)e * ID : snd;
  __shared__ float red[256];
  float xv[8]; float ss = 0.f;
#pragma unroll
  for (int i = 0; i < 8; ++i) {
    float v = __bfloat162float(hidden[(size_t)r * ID + tid + i * 256]);
    v = clipf(v, -100.f, 100.f);
    xv[i] = v; ss += v * v;
  }
  red[tid] = ss; __syncthreads();
  for (int st = 128; st > 0; st >>= 1) { if (tid < st) red[tid] += red[tid + st]; __syncthreads(); }
  float var = fmaxf(red[0] / (float)ID, 1e-5f);
  __syncthreads();
  float rinv = rsqrtf(var + 1e-5f);
  float xn[8]; float amax = 0.f;
#pragma unroll
  for (int i = 0; i < 8; ++i) {
    float t = clipf(xv[i] * rinv, -10.f, 10.f) * wn[tid + i * 256];
    t = clipf(t, -50.f, 50.f);
    xn[i] = t; amax = fmaxf(amax, fabsf(t));
  }
  red[tid] = amax; __syncthreads();
  for (int st = 128; st > 0; st >>= 1) { if (tid < st) red[tid] = fmaxf(red[tid], red[tid + st]); __syncthreads(); }
  float mx = fmaxf(red[0], 1e-4f);
  __syncthreads();
  float sc = 127.f / mx;
#pragma unroll
  for (int i = 0; i < 8; ++i)
    hq[(size_t)r * ID + tid + i * 256] = (signed char)(int)clipf(rintf(xn[i] * sc), -128.f, 127.f);
  if (tid == 0) invh[r] = 1.f / sc;
}

// ---------------- down int8 GEMM + weighted scatter-add ----------------
__global__ __launch_bounds__(256, 3)
void k_gemm_down(const signed char* __restrict__ hq, const signed char* __restrict__ tw,
                 const float* __restrict__ wscale, const float* __restrict__ invh,
                 const int* __restrict__ rows_token, const float* __restrict__ rows_w,
                 const int* __restrict__ rows_expert, const int* __restrict__ offs,
                 float* __restrict__ out) {
  int n0 = blockIdx.x * BM;
  int row0 = blockIdx.y * BM;
  if (row0 >= offs[NE]) return;
  int e = rows_expert[row0];
  int md = (e < NE) ? 16 + e : 26;
  const signed char* wdp = tw + (size_t)md * MSIZE;
  __shared__ __align__(16) signed char As[2 * BM * BK];
  __shared__ __align__(16) signed char Bs[2 * BM * BK];
  __shared__ float s_f[BM];
  __shared__ int s_tok[BM];
  int tid = threadIdx.x, wv = tid >> 6, ln = tid & 63;
  if (tid < BM) {
    s_f[tid] = invh[row0 + tid] * rows_w[row0 + tid];
    s_tok[tid] = rows_token[row0 + tid];
  }
  v4i acc[4][4] = {};
  int lr = ln >> 2;
  int swz = (((ln & 3) ^ ((lr >> 1) & 3)) << 4);
  const signed char* pa[2]; const signed char* pb[2];
#pragma unroll
  for (int j = 0; j < 2; ++j) {
    int row = (wv * 2 + j) * 16 + lr;
    pa[j] = hq + (size_t)(row0 + row) * ID + swz;
    pb[j] = wdp + (size_t)(n0 + row) * ID + swz;
  }
  int wm = (wv & 1) * 64, wn = (wv >> 1) * 64;
  int fm = ln & 15;
  int slot16 = (((ln >> 4) ^ ((fm >> 1) & 3)) << 4);
  int offA[4], offB[4];
#pragma unroll
  for (int i = 0; i < 4; ++i) offA[i] = (wm + i * 16 + fm) * BK + slot16;
#pragma unroll
  for (int j = 0; j < 4; ++j) offB[j] = (wn + j * 16 + fm) * BK + slot16;

  auto stage = [&](int buf) {
#pragma unroll
    for (int j = 0; j < 2; ++j) {
      int co = buf * 8192 + (wv * 2 + j) * 1024;
      g2lds16(pa[j], &As[co]);
      g2lds16(pb[j], &Bs[co]);
      pa[j] += BK; pb[j] += BK;
    }
  };
  auto compute = [&](int buf) {
    int lb = buf * 8192;
    v4i a[4];
#pragma unroll
    for (int i = 0; i < 4; ++i) a[i] = *(const v4i*)&As[lb + offA[i]];
#pragma unroll
    for (int j = 0; j < 4; ++j) {
      v4i b = *(const v4i*)&Bs[lb + offB[j]];
#pragma unroll
      for (int i = 0; i < 4; ++i)
        acc[i][j] = __builtin_amdgcn_mfma_i32_16x16x64_i8(a[i], b, acc[i][j], 0, 0, 0);
    }
  };

  const int NIT = ID / BK;  // 32
  stage(0);
#pragma unroll 1
  for (int it = 0; it < NIT; it += 2) {
    __syncthreads();
    if (it + 1 < NIT) stage(1);
    compute(0);
    __syncthreads();
    if (it + 2 < NIT) stage(0);
    compute(1);
  }

  float ds = wscale[md];
  int dq = (ln >> 4) * 4, dn = ln & 15;
  for (int i = 0; i < 4; ++i) {
#pragma unroll
    for (int rg = 0; rg < 4; ++rg) {
      int lrow = wm + i * 16 + dq + rg;
      int tok = s_tok[lrow];
      if (tok < 0) continue;
      float f = ds * s_f[lrow];
#pragma unroll
      for (int j = 0; j < 4; ++j) {
        int gcol = n0 + wn + j * 16 + dn;
        atomicAdd(&out[(size_t)tok * HD + gcol], (float)acc[i][j][rg] * f);
      }
    }
  }
}

__global__ void k_clip(float* __restrict__ out, int n) {
  for (int i = blockIdx.x * blockDim.x + threadIdx.x; i < n; i += gridDim.x * blockDim.x)
    out[i] = clipf(out[i], -10000.f, 10000.f);
}

// ---------------- host launcher ----------------
extern "C" void kernel_launch(void* const* d_in, const int* in_sizes, int n_in,
                              void* d_out, int out_size, void* d_ws, size_t ws_size,
                              hipStream_t stream) {
  (void)in_sizes; (void)n_in; (void)out_size; (void)ws_size;
  const float* x   = (const float*)d_in[0];
  const float* rw  = (const float*)d_in[1];
  const float* rb  = (const float*)d_in[2];
  const float* Wg  = (const float*)d_in[3];
  const float* Wu  = (const float*)d_in[4];
  const float* Wd  = (const float*)d_in[5];
  const float* ng  = (const float*)d_in[6];
  const float* nu  = (const float*)d_in[7];
  const float* nd  = (const float*)d_in[8];
  const float* sWg = (const float*)d_in[9];
  const float* sWu = (const float*)d_in[10];
  const float* sWd = (const float*)d_in[11];
  const float* sng = (const float*)d_in[12];
  const float* snu = (const float*)d_in[13];
  const float* snd = (const float*)d_in[14];
  float* out = (float*)d_out;
  float* logits = out + (size_t)TOK * HD;

  char* ws = (char*)d_ws;
  size_t off = 0;
  auto alloc = [&](size_t b) { size_t o = off; off = (off + b + 255) & ~(size_t)255; return o; };
  signed char* tw   = (signed char*)(ws + alloc((size_t)27 * MSIZE));
  double* stats     = (double*)(ws + alloc(27 * 2 * sizeof(double)));
  double* wmean     = (double*)(ws + alloc(27 * sizeof(double)));
  float* wscale     = (float*)(ws + alloc(27 * sizeof(float)));
  int* counts       = (int*)(ws + alloc(8 * sizeof(int)));
  int* fill         = (int*)(ws + alloc(8 * sizeof(int)));
  int* offs         = (int*)(ws + alloc(16 * sizeof(int)));
  int* top_idx      = (int*)(ws + alloc((size_t)TOK * 2 * sizeof(int)));
  float* top_w      = (float*)(ws + alloc((size_t)TOK * 2 * sizeof(float)));
  int* rows_token   = (int*)(ws + alloc((size_t)R_MAX * sizeof(int)));
  float* rows_w     = (float*)(ws + alloc((size_t)R_MAX * sizeof(float)));
  int* rows_expert  = (int*)(ws + alloc((size_t)R_MAX * sizeof(int)));
  float* invg       = (float*)(ws + alloc((size_t)R_MAX * sizeof(float)));
  float* invu       = (float*)(ws + alloc((size_t)R_MAX * sizeof(float)));
  float* invh       = (float*)(ws + alloc((size_t)R_MAX * sizeof(float)));
  // hq region; xqg/xqu alias its front (safe: xq consumed by k_gemm_gu before k_hquant writes hq)
  signed char* hq   = (signed char*)(ws + alloc((size_t)R_MAX * ID));
  signed char* xqg  = hq;
  signed char* xqu  = hq + (size_t)R_MAX * HD;
  __hip_bfloat16* hidden = (__hip_bfloat16*)(ws + alloc((size_t)R_MAX * ID * 2));

  hipMemsetAsync(stats, 0, 27 * 2 * sizeof(double), stream);
  hipMemsetAsync(counts, 0, 8 * sizeof(int), stream);
  hipMemsetAsync(out, 0, (size_t)TOK * HD * sizeof(float), stream);

  k_wstats<<<dim3(64, 27), 256, 0, stream>>>(Wg, Wu, Wd, sWg, sWu, sWd, stats);
  k_wfinal<<<1, 32, 0, stream>>>(stats, wmean, wscale);
  k_wquant<<<dim3(256, 27), 256, 0, stream>>>(Wg, Wu, Wd, sWg, sWu, sWd, wmean, tw);
  k_router<<<TOK, 64, 0, stream>>>(x, rw, rb, logits, top_idx, top_w, counts);
  k_initrows<<<(R_MAX + 255) / 256, 256, 0, stream>>>(rows_token, rows_w, rows_expert);
  k_offsets<<<1, 64, 0, stream>>>(counts, offs, fill);
  k_scatter<<<TOK / 256, 256, 0, stream>>>(top_idx, top_w, offs, fill, rows_token, rows_w, rows_expert);
  k_actquant<<<R_MAX, 256, 0, stream>>>(x, rows_token, rows_expert, ng, nu, sng, snu,
                                        xqg, xqu, invg, invu);
  k_gemm_gu<<<dim3(ID / BM, R_MAX / BM), 256, 0, stream>>>(xqg, xqu, tw, wscale, invg, invu,
                                                           rows_expert, offs, hidden);
  k_hquant<<<R_MAX, 256, 0, stream>>>(hidden, rows_token, rows_expert, nd, snd, hq, invh);
  k_gemm_down<<<dim3(HD / BM, R_MAX / BM), 256, 0, stream>>>(hq, tw, wscale, invh, rows_token,
                                                             rows_w, rows_expert, offs, out);
  k_clip<<<4096, 256, 0, stream>>>(out, TOK * HD);
}

// Round 3
// 640.642 us; speedup vs baseline: 1.6218x; 1.4297x over previous
//
#include <hip/hip_runtime.h>
#include <hip/hip_bf16.h>
#include <math.h>

#define TOK 8192
#define HD 768
#define ID 2048
#define NE 8
#define MSIZE (2048*768)
#define BM 128
#define BK 64
#define R_SHARED 8192
#define R_MAX 25600   // 8192 shared + 16384 routed + 8*128 max padding, = 200*128

typedef int v4i __attribute__((ext_vector_type(4)));
typedef __attribute__((address_space(1))) void gas_void;
typedef __attribute__((address_space(3))) void las_void;

__device__ __forceinline__ void g2lds16(const void* g, void* l) {
  __builtin_amdgcn_global_load_lds((gas_void*)g, (las_void*)l, 16, 0, 0);
}

__device__ __forceinline__ float clipf(float v, float lo, float hi) {
  return fminf(fmaxf(v, lo), hi);
}

__device__ __forceinline__ const float* matsel(int mat, const float* Wg, const float* Wu,
                                               const float* Wd, const float* sWg,
                                               const float* sWu, const float* sWd) {
  if (mat < 8)  return Wg + (size_t)mat * MSIZE;
  if (mat < 16) return Wu + (size_t)(mat - 8) * MSIZE;
  if (mat < 24) return Wd + (size_t)(mat - 16) * MSIZE;
  if (mat == 24) return sWg;
  if (mat == 25) return sWu;
  return sWd;
}

// ---------------- weight quantization ----------------
__global__ __launch_bounds__(256)
void k_wstats(const float* __restrict__ Wg, const float* __restrict__ Wu,
              const float* __restrict__ Wd, const float* __restrict__ sWg,
              const float* __restrict__ sWu, const float* __restrict__ sWd,
              double* __restrict__ stats) {
  int mat = blockIdx.y;
  const float* p = matsel(mat, Wg, Wu, Wd, sWg, sWu, sWd);
  int tid = threadIdx.x;
  double s = 0.0, sa = 0.0;
  for (size_t i = (size_t)blockIdx.x * 256 + tid; i < (size_t)MSIZE;
       i += (size_t)gridDim.x * 256) {
    double v = (double)p[i];
    s += v; sa += fabs(v);
  }
  __shared__ double rs[256], ra[256];
  rs[tid] = s; ra[tid] = sa; __syncthreads();
  for (int st = 128; st > 0; st >>= 1) {
    if (tid < st) { rs[tid] += rs[tid + st]; ra[tid] += ra[tid + st]; }
    __syncthreads();
  }
  if (tid == 0) {
    atomicAdd(&stats[mat * 2 + 0], rs[0]);
    atomicAdd(&stats[mat * 2 + 1], ra[0]);
  }
}

__global__ void k_wfinal(const double* __restrict__ stats, double* __restrict__ wmean,
                         float* __restrict__ wscale) {
  int m = threadIdx.x;
  if (m < 27) {
    wmean[m] = stats[m * 2] / (double)MSIZE;
    double sc = stats[m * 2 + 1] / (double)MSIZE;
    wscale[m] = (float)fmax(sc, 1e-8);
  }
}

__global__ __launch_bounds__(256)
void k_wquant(const float* __restrict__ Wg, const float* __restrict__ Wu,
              const float* __restrict__ Wd, const float* __restrict__ sWg,
              const float* __restrict__ sWu, const float* __restrict__ sWd,
              const double* __restrict__ wmean, signed char* __restrict__ tw) {
  int mat = blockIdx.y;
  const float* p = matsel(mat, Wg, Wu, Wd, sWg, sWu, sWd);
  const float4* p4 = (const float4*)p;
  int* t4 = (int*)(tw + (size_t)mat * MSIZE);
  double mu = wmean[mat];
  for (int i = blockIdx.x * 256 + threadIdx.x; i < MSIZE / 4; i += gridDim.x * 256) {
    float4 v = p4[i];
    int b0 = ((double)v.x > mu) ? 1 : (((double)v.x < mu) ? -1 : 0);
    int b1 = ((double)v.y > mu) ? 1 : (((double)v.y < mu) ? -1 : 0);
    int b2 = ((double)v.z > mu) ? 1 : (((double)v.z < mu) ? -1 : 0);
    int b3 = ((double)v.w > mu) ? 1 : (((double)v.w < mu) ? -1 : 0);
    t4[i] = (b0 & 255) | ((b1 & 255) << 8) | ((b2 & 255) << 16) | ((b3 & 255) << 24);
  }
}

// ---------------- router (NO atomics — that was 200 us of contention) -------
__global__ __launch_bounds__(256)
void k_router(const float* __restrict__ x, const float* __restrict__ rw,
              const float* __restrict__ rb, float* __restrict__ logits,
              int* __restrict__ top_idx, float* __restrict__ top_w) {
  int wv = threadIdx.x >> 6, ln = threadIdx.x & 63;
  int t = blockIdx.x * 4 + wv;
  const float4* xr = (const float4*)(x + (size_t)t * HD);
  const float4* rw4 = (const float4*)rw;
  float acc[NE] = {};
#pragma unroll
  for (int i = 0; i < 3; ++i) {
    float4 xv = xr[ln + i * 64];
#pragma unroll
    for (int e = 0; e < NE; ++e) {
      float4 w4 = rw4[e * 192 + ln + i * 64];
      acc[e] += xv.x * w4.x + xv.y * w4.y + xv.z * w4.z + xv.w * w4.w;
    }
  }
#pragma unroll
  for (int e = 0; e < NE; ++e) {
    float v = acc[e];
#pragma unroll
    for (int o = 32; o > 0; o >>= 1) v += __shfl_down(v, o, 64);
    acc[e] = v;
  }
  if (ln == 0) {
    float lg[NE], m = -1e30f;
#pragma unroll
    for (int e = 0; e < NE; ++e) {
      lg[e] = acc[e] + rb[e];
      logits[(size_t)t * NE + e] = lg[e];
      m = fmaxf(m, lg[e]);
    }
    float p[NE], s = 0.f;
#pragma unroll
    for (int e = 0; e < NE; ++e) { p[e] = expf(lg[e] - m); s += p[e]; }
    float inv = 1.f / s;
#pragma unroll
    for (int e = 0; e < NE; ++e) p[e] *= inv;
    int e1 = 0; float b1 = p[0];
    for (int e = 1; e < NE; ++e) if (p[e] > b1) { b1 = p[e]; e1 = e; }
    int e2 = -1; float b2 = -1.f;
    for (int e = 0; e < NE; ++e) if (e != e1 && p[e] > b2) { b2 = p[e]; e2 = e; }
    float sw = b1 + b2 + 1e-8f;
    top_idx[t * 2 + 0] = e1; top_idx[t * 2 + 1] = e2;
    top_w[t * 2 + 0] = b1 / sw; top_w[t * 2 + 1] = b2 / sw;
  }
}

// single-block LDS histogram of expert assignments
__global__ __launch_bounds__(1024)
void k_hist(const int* __restrict__ top_idx, int* __restrict__ counts) {
  __shared__ int h[NE];
  if (threadIdx.x < NE) h[threadIdx.x] = 0;
  __syncthreads();
  for (int i = threadIdx.x; i < TOK * 2; i += 1024) atomicAdd(&h[top_idx[i]], 1);
  __syncthreads();
  if (threadIdx.x < NE) counts[threadIdx.x] = h[threadIdx.x];
}

__global__ void k_initrows(int* __restrict__ rows_token, float* __restrict__ rows_w,
                           int* __restrict__ rows_expert) {
  int r = blockIdx.x * blockDim.x + threadIdx.x;
  if (r >= R_MAX) return;
  if (r < R_SHARED) { rows_token[r] = r; rows_w[r] = 1.f; rows_expert[r] = NE; }
  else { rows_token[r] = -1; rows_w[r] = 0.f; rows_expert[r] = 0; }
}

__global__ void k_offsets(const int* __restrict__ counts, int* __restrict__ offs,
                          int* __restrict__ fill) {
  if (threadIdx.x == 0) {
    int off = R_SHARED;
    for (int e = 0; e < NE; ++e) {
      offs[e] = off;
      off += ((counts[e] + BM - 1) / BM) * BM;
    }
    offs[NE] = off;
  }
  if (threadIdx.x < NE) fill[threadIdx.x] = 0;
}

// wave-aggregated scatter: one atomic per (wave, expert) instead of per token
__global__ __launch_bounds__(256)
void k_scatter(const int* __restrict__ top_idx, const float* __restrict__ top_w,
               const int* __restrict__ offs, int* __restrict__ fill,
               int* __restrict__ rows_token, float* __restrict__ rows_w,
               int* __restrict__ rows_expert, int* __restrict__ inv_row) {
  int t = blockIdx.x * 256 + threadIdx.x;
  int ln = threadIdx.x & 63;
  unsigned long long lt = (ln == 63) ? 0x7fffffffffffffffull
                                     : ((1ull << ln) - 1);
#pragma unroll
  for (int k = 0; k < 2; ++k) {
    int e = top_idx[t * 2 + k];
    unsigned long long peers = 0;
#pragma unroll
    for (int ee = 0; ee < NE; ++ee) {
      unsigned long long m = __ballot(e == ee);
      if (e == ee) peers = m;
    }
    int lead = __ffsll(peers) - 1;
    int rank = __popcll(peers & lt);
    int base = 0;
    if (ln == lead) base = atomicAdd(&fill[e], __popcll(peers));
    base = __shfl(base, lead, 64);
    int r = offs[e] + base + rank;
    rows_token[r] = t;
    rows_w[r] = top_w[t * 2 + k];
    rows_expert[r] = e;
    inv_row[t * 2 + k] = r;
  }
}

// ---------------- activation quant (x -> xq_g, xq_u) ----------------
__global__ __launch_bounds__(256)
void k_actquant(const float* __restrict__ x, const int* __restrict__ rows_token,
                const int* __restrict__ rows_expert, const float* __restrict__ ng,
                const float* __restrict__ nu, const float* __restrict__ sng,
                const float* __restrict__ snu, signed char* __restrict__ xqg,
                signed char* __restrict__ xqu, float* __restrict__ invg,
                float* __restrict__ invu) {
  int r = blockIdx.x, tid = threadIdx.x;
  int tok = rows_token[r];
  if (tok < 0) {
    for (int i = tid; i < HD; i += 256) {
      xqg[(size_t)r * HD + i] = 0; xqu[(size_t)r * HD + i] = 0;
    }
    if (tid == 0) { invg[r] = 0.f; invu[r] = 0.f; }
    return;
  }
  int e = rows_expert[r];
  const float* wg = (e < NE) ? ng + (size_t)e * HD : sng;
  const float* wu = (e < NE) ? nu + (size_t)e * HD : snu;
  __shared__ float red[256];
  float xv[3]; float ss = 0.f;
#pragma unroll
  for (int i = 0; i < 3; ++i) {
    float v = x[(size_t)tok * HD + tid + i * 256];
    v = clipf(v, -100.f, 100.f);
    xv[i] = v; ss += v * v;
  }
  red[tid] = ss; __syncthreads();
  for (int st = 128; st > 0; st >>= 1) { if (tid < st) red[tid] += red[tid + st]; __syncthreads(); }
  float var = fmaxf(red[0] / (float)HD, 1e-5f);
  __syncthreads();
  float rinv = rsqrtf(var + 1e-5f);
  // gate path
  float xn[3]; float amax = 0.f;
#pragma unroll
  for (int i = 0; i < 3; ++i) {
    float t = clipf(xv[i] * rinv, -10.f, 10.f) * wg[tid + i * 256];
    t = clipf(t, -50.f, 50.f);
    xn[i] = t; amax = fmaxf(amax, fabsf(t));
  }
  red[tid] = amax; __syncthreads();
  for (int st = 128; st > 0; st >>= 1) { if (tid < st) red[tid] = fmaxf(red[tid], red[tid + st]); __syncthreads(); }
  float mx = fmaxf(red[0], 1e-4f);
  __syncthreads();
  float sc = 127.f / mx;
#pragma unroll
  for (int i = 0; i < 3; ++i)
    xqg[(size_t)r * HD + tid + i * 256] = (signed char)(int)clipf(rintf(xn[i] * sc), -128.f, 127.f);
  if (tid == 0) invg[r] = 1.f / sc;
  // up path
  amax = 0.f;
#pragma unroll
  for (int i = 0; i < 3; ++i) {
    float t = clipf(xv[i] * rinv, -10.f, 10.f) * wu[tid + i * 256];
    t = clipf(t, -50.f, 50.f);
    xn[i] = t; amax = fmaxf(amax, fabsf(t));
  }
  red[tid] = amax; __syncthreads();
  for (int st = 128; st > 0; st >>= 1) { if (tid < st) red[tid] = fmaxf(red[tid], red[tid + st]); __syncthreads(); }
  mx = fmaxf(red[0], 1e-4f);
  __syncthreads();
  sc = 127.f / mx;
#pragma unroll
  for (int i = 0; i < 3; ++i)
    xqu[(size_t)r * HD + tid + i * 256] = (signed char)(int)clipf(rintf(xn[i] * sc), -128.f, 127.f);
  if (tid == 0) invu[r] = 1.f / sc;
}

// ---------------- fused gate+up int8 GEMM -> hidden (bf16) ----------------
__global__ __launch_bounds__(256, 2)
void k_gemm_gu(const signed char* __restrict__ xqg, const signed char* __restrict__ xqu,
               const signed char* __restrict__ tw, const float* __restrict__ wscale,
               const float* __restrict__ invg, const float* __restrict__ invu,
               const int* __restrict__ rows_expert, const int* __restrict__ offs,
               __hip_bfloat16* __restrict__ hidden) {
  int n0 = blockIdx.x * BM;
  int row0 = blockIdx.y * BM;
  if (row0 >= offs[NE]) return;
  int e = rows_expert[row0];
  int mg = (e < NE) ? e : 24;
  int mu = (e < NE) ? e + 8 : 25;
  const signed char* wgp = tw + (size_t)mg * MSIZE;
  const signed char* wup = tw + (size_t)mu * MSIZE;
  __shared__ __align__(16) signed char Ag[2 * BM * BK];
  __shared__ __align__(16) signed char Au[2 * BM * BK];
  __shared__ __align__(16) signed char Bg[2 * BM * BK];
  __shared__ __align__(16) signed char Bu[2 * BM * BK];
  __shared__ float sg[BM], su[BM];
  int tid = threadIdx.x, wv = tid >> 6, ln = tid & 63;
  if (tid < BM) { sg[tid] = invg[row0 + tid]; su[tid] = invu[row0 + tid]; }
  v4i accg[4][4] = {};
  v4i accu[4][4] = {};
  int lr = ln >> 2;
  int swz = (((ln & 3) ^ ((lr >> 1) & 3)) << 4);
  const signed char* pag[2]; const signed char* pau[2];
  const signed char* pbg[2]; const signed char* pbu[2];
#pragma unroll
  for (int j = 0; j < 2; ++j) {
    int row = (wv * 2 + j) * 16 + lr;
    pag[j] = xqg + (size_t)(row0 + row) * HD + swz;
    pau[j] = xqu + (size_t)(row0 + row) * HD + swz;
    pbg[j] = wgp + (size_t)(n0 + row) * HD + swz;
    pbu[j] = wup + (size_t)(n0 + row) * HD + swz;
  }
  int wm = (wv & 1) * 64, wn = (wv >> 1) * 64;
  int fm = ln & 15;
  int slot16 = (((ln >> 4) ^ ((fm >> 1) & 3)) << 4);
  int offA[4], offB[4];
#pragma unroll
  for (int i = 0; i < 4; ++i) offA[i] = (wm + i * 16 + fm) * BK + slot16;
#pragma unroll
  for (int j = 0; j < 4; ++j) offB[j] = (wn + j * 16 + fm) * BK + slot16;

  auto stage = [&](int buf) {
#pragma unroll
    for (int j = 0; j < 2; ++j) {
      int co = buf * 8192 + (wv * 2 + j) * 1024;
      g2lds16(pag[j], &Ag[co]);
      g2lds16(pau[j], &Au[co]);
      g2lds16(pbg[j], &Bg[co]);
      g2lds16(pbu[j], &Bu[co]);
      pag[j] += BK; pau[j] += BK; pbg[j] += BK; pbu[j] += BK;
    }
  };
  auto compute = [&](int buf) {
    int lb = buf * 8192;
    v4i ag[4], au[4];
#pragma unroll
    for (int i = 0; i < 4; ++i) {
      ag[i] = *(const v4i*)&Ag[lb + offA[i]];
      au[i] = *(const v4i*)&Au[lb + offA[i]];
    }
#pragma unroll
    for (int j = 0; j < 4; ++j) {
      v4i bg = *(const v4i*)&Bg[lb + offB[j]];
      v4i bu = *(const v4i*)&Bu[lb + offB[j]];
#pragma unroll
      for (int i = 0; i < 4; ++i) {
        accg[i][j] = __builtin_amdgcn_mfma_i32_16x16x64_i8(ag[i], bg, accg[i][j], 0, 0, 0);
        accu[i][j] = __builtin_amdgcn_mfma_i32_16x16x64_i8(au[i], bu, accu[i][j], 0, 0, 0);
      }
    }
  };

  const int NIT = HD / BK;  // 12
  stage(0);
#pragma unroll 1
  for (int it = 0; it < NIT; it += 2) {
    __syncthreads();
    if (it + 1 < NIT) stage(1);
    compute(0);
    __syncthreads();
    if (it + 2 < NIT) stage(0);
    compute(1);
  }

  float gs = wscale[mg], us = wscale[mu];
  int dq = (ln >> 4) * 4, dn = ln & 15;
  for (int i = 0; i < 4; ++i) {
#pragma unroll
    for (int rg = 0; rg < 4; ++rg) {
      int lrow = wm + i * 16 + dq + rg;
      int grow = row0 + lrow;
      float ig = gs * sg[lrow];
      float iu = us * su[lrow];
#pragma unroll
      for (int j = 0; j < 4; ++j) {
        int gcol = n0 + wn + j * 16 + dn;
        float g = (float)accg[i][j][rg] * ig;
        g = clipf(g, -20.f, 20.f);
        float sil = g / (1.f + expf(-g));
        float u = (float)accu[i][j][rg] * iu;
        float h = clipf(sil * u, -1000.f, 1000.f);
        hidden[(size_t)grow * ID + gcol] = __float2bfloat16(h);
      }
    }
  }
}

// ---------------- hidden quant ----------------
__global__ __launch_bounds__(256)
void k_hquant(const __hip_bfloat16* __restrict__ hidden, const int* __restrict__ rows_token,
              const int* __restrict__ rows_expert, const float* __restrict__ nd,
              const float* __restrict__ snd, signed char* __restrict__ hq,
              float* __restrict__ invh) {
  int r = blockIdx.x, tid = threadIdx.x;
  int tok = rows_token[r];
  if (tok < 0) {
    for (int i = tid; i < ID; i += 256) hq[(size_t)r * ID + i] = 0;
    if (tid == 0) invh[r] = 0.f;
    return;
  }
  int e = rows_expert[r];
  const float* wn = (e < NE) ? nd + (size_t)e * ID : snd;
  __shared__ float red[256];
  float xv[8]; float ss = 0.f;
#pragma unroll
  for (int i = 0; i < 8; ++i) {
    float v = __bfloat162float(hidden[(size_t)r * ID + tid + i * 256]);
    v = clipf(v, -100.f, 100.f);
    xv[i] = v; ss += v * v;
  }
  red[tid] = ss; __syncthreads();
  for (int st = 128; st > 0; st >>= 1) { if (tid < st) red[tid] += red[tid + st]; __syncthreads(); }
  float var = fmaxf(red[0] / (float)ID, 1e-5f);
  __syncthreads();
  float rinv = rsqrtf(var + 1e-5f);
  float xn[8]; float amax = 0.f;
#pragma unroll
  for (int i = 0; i < 8; ++i) {
    float t = clipf(xv[i] * rinv, -10.f, 10.f) * wn[tid + i * 256];
    t = clipf(t, -50.f, 50.f);
    xn[i] = t; amax = fmaxf(amax, fabsf(t));
  }
  red[tid] = amax; __syncthreads();
  for (int st = 128; st > 0; st >>= 1) { if (tid < st) red[tid] = fmaxf(red[tid], red[tid + st]); __syncthreads(); }
  float mx = fmaxf(red[0], 1e-4f);
  __syncthreads();
  float sc = 127.f / mx;
#pragma unroll
  for (int i = 0; i < 8; ++i)
    hq[(size_t)r * ID + tid + i * 256] = (signed char)(int)clipf(rintf(xn[i] * sc), -128.f, 127.f);
  if (tid == 0) invh[r] = 1.f / sc;
}

// ---------------- down int8 GEMM -> y (per-assignment-row, plain stores) ----
__global__ __launch_bounds__(256, 3)
void k_gemm_down(const signed char* __restrict__ hq, const signed char* __restrict__ tw,
                 const float* __restrict__ wscale, const float* __restrict__ invh,
                 const float* __restrict__ rows_w, const int* __restrict__ rows_expert,
                 const int* __restrict__ offs, float* __restrict__ y) {
  int n0 = blockIdx.x * BM;
  int row0 = blockIdx.y * BM;
  if (row0 >= offs[NE]) return;
  int e = rows_expert[row0];
  int md = (e < NE) ? 16 + e : 26;
  const signed char* wdp = tw + (size_t)md * MSIZE;
  __shared__ __align__(16) signed char As[2 * BM * BK];
  __shared__ __align__(16) signed char Bs[2 * BM * BK];
  __shared__ float s_f[BM];
  int tid = threadIdx.x, wv = tid >> 6, ln = tid & 63;
  if (tid < BM) s_f[tid] = invh[row0 + tid] * rows_w[row0 + tid];
  v4i acc[4][4] = {};
  int lr = ln >> 2;
  int swz = (((ln & 3) ^ ((lr >> 1) & 3)) << 4);
  const signed char* pa[2]; const signed char* pb[2];
#pragma unroll
  for (int j = 0; j < 2; ++j) {
    int row = (wv * 2 + j) * 16 + lr;
    pa[j] = hq + (size_t)(row0 + row) * ID + swz;
    pb[j] = wdp + (size_t)(n0 + row) * ID + swz;
  }
  int wm = (wv & 1) * 64, wn = (wv >> 1) * 64;
  int fm = ln & 15;
  int slot16 = (((ln >> 4) ^ ((fm >> 1) & 3)) << 4);
  int offA[4], offB[4];
#pragma unroll
  for (int i = 0; i < 4; ++i) offA[i] = (wm + i * 16 + fm) * BK + slot16;
#pragma unroll
  for (int j = 0; j < 4; ++j) offB[j] = (wn + j * 16 + fm) * BK + slot16;

  auto stage = [&](int buf) {
#pragma unroll
    for (int j = 0; j < 2; ++j) {
      int co = buf * 8192 + (wv * 2 + j) * 1024;
      g2lds16(pa[j], &As[co]);
      g2lds16(pb[j], &Bs[co]);
      pa[j] += BK; pb[j] += BK;
    }
  };
  auto compute = [&](int buf) {
    int lb = buf * 8192;
    v4i a[4];
#pragma unroll
    for (int i = 0; i < 4; ++i) a[i] = *(const v4i*)&As[lb + offA[i]];
#pragma unroll
    for (int j = 0; j < 4; ++j) {
      v4i b = *(const v4i*)&Bs[lb + offB[j]];
#pragma unroll
      for (int i = 0; i < 4; ++i)
        acc[i][j] = __builtin_amdgcn_mfma_i32_16x16x64_i8(a[i], b, acc[i][j], 0, 0, 0);
    }
  };

  const int NIT = ID / BK;  // 32
  stage(0);
#pragma unroll 1
  for (int it = 0; it < NIT; it += 2) {
    __syncthreads();
    if (it + 1 < NIT) stage(1);
    compute(0);
    __syncthreads();
    if (it + 2 < NIT) stage(0);
    compute(1);
  }

  float ds = wscale[md];
  int dq = (ln >> 4) * 4, dn = ln & 15;
  for (int i = 0; i < 4; ++i) {
#pragma unroll
    for (int rg = 0; rg < 4; ++rg) {
      int lrow = wm + i * 16 + dq + rg;
      float f = ds * s_f[lrow];
#pragma unroll
      for (int j = 0; j < 4; ++j) {
        int gcol = n0 + wn + j * 16 + dn;
        y[(size_t)(row0 + lrow) * HD + gcol] = (float)acc[i][j][rg] * f;
      }
    }
  }
}

// ---------------- final gather: out[t] = clip(y[t] + y[r1] + y[r2]) ---------
__global__ __launch_bounds__(192)
void k_gather(const float* __restrict__ y, const int* __restrict__ inv_row,
              float* __restrict__ out) {
  int t = blockIdx.x, c = threadIdx.x;
  int r1 = inv_row[t * 2 + 0], r2 = inv_row[t * 2 + 1];
  const float4* y4 = (const float4*)y;
  float4 a = y4[(size_t)t * 192 + c];
  float4 b = y4[(size_t)r1 * 192 + c];
  float4 d = y4[(size_t)r2 * 192 + c];
  float4 o;
  o.x = clipf(a.x + b.x + d.x, -10000.f, 10000.f);
  o.y = clipf(a.y + b.y + d.y, -10000.f, 10000.f);
  o.z = clipf(a.z + b.z + d.z, -10000.f, 10000.f);
  o.w = clipf(a.w + b.w + d.w, -10000.f, 10000.f);
  ((float4*)out)[(size_t)t * 192 + c] = o;
}

// ---------------- host launcher ----------------
extern "C" void kernel_launch(void* const* d_in, const int* in_sizes, int n_in,
                              void* d_out, int out_size, void* d_ws, size_t ws_size,
                              hipStream_t stream) {
  (void)in_sizes; (void)n_in; (void)out_size; (void)ws_size;
  const float* x   = (const float*)d_in[0];
  const float* rw  = (const float*)d_in[1];
  const float* rb  = (const float*)d_in[2];
  const float* Wg  = (const float*)d_in[3];
  const float* Wu  = (const float*)d_in[4];
  const float* Wd  = (const float*)d_in[5];
  const float* ng  = (const float*)d_in[6];
  const float* nu  = (const float*)d_in[7];
  const float* nd  = (const float*)d_in[8];
  const float* sWg = (const float*)d_in[9];
  const float* sWu = (const float*)d_in[10];
  const float* sWd = (const float*)d_in[11];
  const float* sng = (const float*)d_in[12];
  const float* snu = (const float*)d_in[13];
  const float* snd = (const float*)d_in[14];
  float* out = (float*)d_out;
  float* logits = out + (size_t)TOK * HD;

  char* ws = (char*)d_ws;
  size_t off = 0;
  auto alloc = [&](size_t b) { size_t o = off; off = (off + b + 255) & ~(size_t)255; return o; };
  signed char* tw   = (signed char*)(ws + alloc((size_t)27 * MSIZE));
  double* stats     = (double*)(ws + alloc(27 * 2 * sizeof(double)));
  double* wmean     = (double*)(ws + alloc(27 * sizeof(double)));
  float* wscale     = (float*)(ws + alloc(27 * sizeof(float)));
  int* counts       = (int*)(ws + alloc(8 * sizeof(int)));
  int* fill         = (int*)(ws + alloc(8 * sizeof(int)));
  int* offs         = (int*)(ws + alloc(16 * sizeof(int)));
  int* top_idx      = (int*)(ws + alloc((size_t)TOK * 2 * sizeof(int)));
  float* top_w      = (float*)(ws + alloc((size_t)TOK * 2 * sizeof(float)));
  int* inv_row      = (int*)(ws + alloc((size_t)TOK * 2 * sizeof(int)));
  int* rows_token   = (int*)(ws + alloc((size_t)R_MAX * sizeof(int)));
  float* rows_w     = (float*)(ws + alloc((size_t)R_MAX * sizeof(float)));
  int* rows_expert  = (int*)(ws + alloc((size_t)R_MAX * sizeof(int)));
  float* invg       = (float*)(ws + alloc((size_t)R_MAX * sizeof(float)));
  float* invu       = (float*)(ws + alloc((size_t)R_MAX * sizeof(float)));
  float* invh       = (float*)(ws + alloc((size_t)R_MAX * sizeof(float)));
  // hq region; xqg/xqu alias its front (safe: xq consumed by k_gemm_gu before k_hquant writes hq)
  signed char* hq   = (signed char*)(ws + alloc((size_t)R_MAX * ID));
  signed char* xqg  = hq;
  signed char* xqu  = hq + (size_t)R_MAX * HD;
  // hidden region; y (fp32 down-GEMM output, R_MAX*HD*4 = 78 MB) aliases it —
  // hidden (105 MB) is dead after k_hquant, before k_gemm_down writes y.
  char* hid_region  = ws + alloc((size_t)R_MAX * ID * 2);
  __hip_bfloat16* hidden = (__hip_bfloat16*)hid_region;
  float* y          = (float*)hid_region;

  hipMemsetAsync(stats, 0, 27 * 2 * sizeof(double), stream);

  k_wstats<<<dim3(64, 27), 256, 0, stream>>>(Wg, Wu, Wd, sWg, sWu, sWd, stats);
  k_wfinal<<<1, 32, 0, stream>>>(stats, wmean, wscale);
  k_wquant<<<dim3(256, 27), 256, 0, stream>>>(Wg, Wu, Wd, sWg, sWu, sWd, wmean, tw);
  k_router<<<TOK / 4, 256, 0, stream>>>(x, rw, rb, logits, top_idx, top_w);
  k_hist<<<1, 1024, 0, stream>>>(top_idx, counts);
  k_initrows<<<(R_MAX + 255) / 256, 256, 0, stream>>>(rows_token, rows_w, rows_expert);
  k_offsets<<<1, 64, 0, stream>>>(counts, offs, fill);
  k_scatter<<<TOK / 256, 256, 0, stream>>>(top_idx, top_w, offs, fill, rows_token,
                                           rows_w, rows_expert, inv_row);
  k_actquant<<<R_MAX, 256, 0, stream>>>(x, rows_token, rows_expert, ng, nu, sng, snu,
                                        xqg, xqu, invg, invu);
  k_gemm_gu<<<dim3(ID / BM, R_MAX / BM), 256, 0, stream>>>(xqg, xqu, tw, wscale, invg, invu,
                                                           rows_expert, offs, hidden);
  k_hquant<<<R_MAX, 256, 0, stream>>>(hidden, rows_token, rows_expert, nd, snd, hq, invh);
  k_gemm_down<<<dim3(HD / BM, R_MAX / BM), 256, 0, stream>>>(hq, tw, wscale, invh,
                                                             rows_w, rows_expert, offs, y);
  k_gather<<<TOK, 192, 0, stream>>>(y, inv_row, out);
}

// Round 4
// 596.586 us; speedup vs baseline: 1.7416x; 1.0738x over previous
//
#include <hip/hip_runtime.h>
#include <hip/hip_bf16.h>
#include <math.h>

#define TOK 8192
#define HD 768
#define ID 2048
#define NE 8
#define MSIZE (2048*768)
#define BM 128
#define BK 64
#define R_SHARED 8192
#define R_MAX 25600   // 8192 shared + 16384 routed + 8*128 max padding, = 200*128

typedef int v4i __attribute__((ext_vector_type(4)));
typedef __attribute__((address_space(1))) void gas_void;
typedef __attribute__((address_space(3))) void las_void;

__device__ __forceinline__ void g2lds16(const void* g, void* l) {
  __builtin_amdgcn_global_load_lds((gas_void*)g, (las_void*)l, 16, 0, 0);
}

__device__ __forceinline__ float clipf(float v, float lo, float hi) {
  return fminf(fmaxf(v, lo), hi);
}

__device__ __forceinline__ float wred_sum(float v) {
#pragma unroll
  for (int o = 32; o > 0; o >>= 1) v += __shfl_down(v, o, 64);
  return v;
}
__device__ __forceinline__ float wred_max(float v) {
#pragma unroll
  for (int o = 32; o > 0; o >>= 1) v = fmaxf(v, __shfl_down(v, o, 64));
  return v;
}

__device__ __forceinline__ const float* matsel(int mat, const float* Wg, const float* Wu,
                                               const float* Wd, const float* sWg,
                                               const float* sWu, const float* sWd) {
  if (mat < 8)  return Wg + (size_t)mat * MSIZE;
  if (mat < 16) return Wu + (size_t)(mat - 8) * MSIZE;
  if (mat < 24) return Wd + (size_t)(mat - 16) * MSIZE;
  if (mat == 24) return sWg;
  if (mat == 25) return sWu;
  return sWd;
}

// ---------------- weight quantization ----------------
__global__ __launch_bounds__(256)
void k_wstats(const float* __restrict__ Wg, const float* __restrict__ Wu,
              const float* __restrict__ Wd, const float* __restrict__ sWg,
              const float* __restrict__ sWu, const float* __restrict__ sWd,
              double* __restrict__ stats) {
  int mat = blockIdx.y;
  const float* p = matsel(mat, Wg, Wu, Wd, sWg, sWu, sWd);
  int tid = threadIdx.x;
  double s = 0.0, sa = 0.0;
  for (size_t i = (size_t)blockIdx.x * 256 + tid; i < (size_t)MSIZE;
       i += (size_t)gridDim.x * 256) {
    double v = (double)p[i];
    s += v; sa += fabs(v);
  }
  __shared__ double rs[256], ra[256];
  rs[tid] = s; ra[tid] = sa; __syncthreads();
  for (int st = 128; st > 0; st >>= 1) {
    if (tid < st) { rs[tid] += rs[tid + st]; ra[tid] += ra[tid + st]; }
    __syncthreads();
  }
  if (tid == 0) {
    atomicAdd(&stats[mat * 2 + 0], rs[0]);
    atomicAdd(&stats[mat * 2 + 1], ra[0]);
  }
}

__global__ void k_wfinal(const double* __restrict__ stats, double* __restrict__ wmean,
                         float* __restrict__ wscale) {
  int m = threadIdx.x;
  if (m < 27) {
    wmean[m] = stats[m * 2] / (double)MSIZE;
    double sc = stats[m * 2 + 1] / (double)MSIZE;
    wscale[m] = (float)fmax(sc, 1e-8);
  }
}

__global__ __launch_bounds__(256)
void k_wquant(const float* __restrict__ Wg, const float* __restrict__ Wu,
              const float* __restrict__ Wd, const float* __restrict__ sWg,
              const float* __restrict__ sWu, const float* __restrict__ sWd,
              const double* __restrict__ wmean, signed char* __restrict__ tw) {
  int mat = blockIdx.y;
  const float* p = matsel(mat, Wg, Wu, Wd, sWg, sWu, sWd);
  const float4* p4 = (const float4*)p;
  int* t4 = (int*)(tw + (size_t)mat * MSIZE);
  double mu = wmean[mat];
  for (int i = blockIdx.x * 256 + threadIdx.x; i < MSIZE / 4; i += gridDim.x * 256) {
    float4 v = p4[i];
    int b0 = ((double)v.x > mu) ? 1 : (((double)v.x < mu) ? -1 : 0);
    int b1 = ((double)v.y > mu) ? 1 : (((double)v.y < mu) ? -1 : 0);
    int b2 = ((double)v.z > mu) ? 1 : (((double)v.z < mu) ? -1 : 0);
    int b3 = ((double)v.w > mu) ? 1 : (((double)v.w < mu) ? -1 : 0);
    t4[i] = (b0 & 255) | ((b1 & 255) << 8) | ((b2 & 255) << 16) | ((b3 & 255) << 24);
  }
}

// ---------------- router ----------------
__global__ __launch_bounds__(256)
void k_router(const float* __restrict__ x, const float* __restrict__ rw,
              const float* __restrict__ rb, float* __restrict__ logits,
              int* __restrict__ top_idx, float* __restrict__ top_w) {
  int wv = threadIdx.x >> 6, ln = threadIdx.x & 63;
  int t = blockIdx.x * 4 + wv;
  const float4* xr = (const float4*)(x + (size_t)t * HD);
  const float4* rw4 = (const float4*)rw;
  float acc[NE] = {};
#pragma unroll
  for (int i = 0; i < 3; ++i) {
    float4 xv = xr[ln + i * 64];
#pragma unroll
    for (int e = 0; e < NE; ++e) {
      float4 w4 = rw4[e * 192 + ln + i * 64];
      acc[e] += xv.x * w4.x + xv.y * w4.y + xv.z * w4.z + xv.w * w4.w;
    }
  }
#pragma unroll
  for (int e = 0; e < NE; ++e) acc[e] = wred_sum(acc[e]);
  if (ln == 0) {
    float lg[NE], m = -1e30f;
#pragma unroll
    for (int e = 0; e < NE; ++e) {
      lg[e] = acc[e] + rb[e];
      logits[(size_t)t * NE + e] = lg[e];
      m = fmaxf(m, lg[e]);
    }
    float p[NE], s = 0.f;
#pragma unroll
    for (int e = 0; e < NE; ++e) { p[e] = expf(lg[e] - m); s += p[e]; }
    float inv = 1.f / s;
#pragma unroll
    for (int e = 0; e < NE; ++e) p[e] *= inv;
    int e1 = 0; float b1 = p[0];
    for (int e = 1; e < NE; ++e) if (p[e] > b1) { b1 = p[e]; e1 = e; }
    int e2 = -1; float b2 = -1.f;
    for (int e = 0; e < NE; ++e) if (e != e1 && p[e] > b2) { b2 = p[e]; e2 = e; }
    float sw = b1 + b2 + 1e-8f;
    top_idx[t * 2 + 0] = e1; top_idx[t * 2 + 1] = e2;
    top_w[t * 2 + 0] = b1 / sw; top_w[t * 2 + 1] = b2 / sw;
  }
}

// single-block LDS histogram of expert assignments
__global__ __launch_bounds__(1024)
void k_hist(const int* __restrict__ top_idx, int* __restrict__ counts) {
  __shared__ int h[NE];
  if (threadIdx.x < NE) h[threadIdx.x] = 0;
  __syncthreads();
  for (int i = threadIdx.x; i < TOK * 2; i += 1024) atomicAdd(&h[top_idx[i]], 1);
  __syncthreads();
  if (threadIdx.x < NE) counts[threadIdx.x] = h[threadIdx.x];
}

__global__ void k_initrows(int* __restrict__ rows_token, float* __restrict__ rows_w,
                           int* __restrict__ rows_expert) {
  int r = blockIdx.x * blockDim.x + threadIdx.x;
  if (r >= R_MAX) return;
  if (r < R_SHARED) { rows_token[r] = r; rows_w[r] = 1.f; rows_expert[r] = NE; }
  else { rows_token[r] = -1; rows_w[r] = 0.f; rows_expert[r] = 0; }
}

__global__ void k_offsets(const int* __restrict__ counts, int* __restrict__ offs,
                          int* __restrict__ fill) {
  if (threadIdx.x == 0) {
    int off = R_SHARED;
    for (int e = 0; e < NE; ++e) {
      offs[e] = off;
      off += ((counts[e] + BM - 1) / BM) * BM;
    }
    offs[NE] = off;
  }
  if (threadIdx.x < NE) fill[threadIdx.x] = 0;
}

// wave-aggregated scatter: one atomic per (wave, expert) instead of per token
__global__ __launch_bounds__(256)
void k_scatter(const int* __restrict__ top_idx, const float* __restrict__ top_w,
               const int* __restrict__ offs, int* __restrict__ fill,
               int* __restrict__ rows_token, float* __restrict__ rows_w,
               int* __restrict__ rows_expert, int* __restrict__ inv_row) {
  int t = blockIdx.x * 256 + threadIdx.x;
  int ln = threadIdx.x & 63;
  unsigned long long lt = (ln == 63) ? 0x7fffffffffffffffull
                                     : ((1ull << ln) - 1);
#pragma unroll
  for (int k = 0; k < 2; ++k) {
    int e = top_idx[t * 2 + k];
    unsigned long long peers = 0;
#pragma unroll
    for (int ee = 0; ee < NE; ++ee) {
      unsigned long long m = __ballot(e == ee);
      if (e == ee) peers = m;
    }
    int lead = __ffsll(peers) - 1;
    int rank = __popcll(peers & lt);
    int base = 0;
    if (ln == lead) base = atomicAdd(&fill[e], __popcll(peers));
    base = __shfl(base, lead, 64);
    int r = offs[e] + base + rank;
    rows_token[r] = t;
    rows_w[r] = top_w[t * 2 + k];
    rows_expert[r] = e;
    inv_row[t * 2 + k] = r;
  }
}

// ---------------- activation quant (x -> xq_g, xq_u) ----------------
__global__ __launch_bounds__(256)
void k_actquant(const float* __restrict__ x, const int* __restrict__ rows_token,
                const int* __restrict__ rows_expert, const float* __restrict__ ng,
                const float* __restrict__ nu, const float* __restrict__ sng,
                const float* __restrict__ snu, signed char* __restrict__ xqg,
                signed char* __restrict__ xqu, float* __restrict__ invg,
                float* __restrict__ invu) {
  int r = blockIdx.x, tid = threadIdx.x;
  int wv = tid >> 6, ln = tid & 63;
  int tok = rows_token[r];
  if (tok < 0) {
    if (tid < 192) {
      ((int*)(xqg + (size_t)r * HD))[tid] = 0;
      ((int*)(xqu + (size_t)r * HD))[tid] = 0;
    }
    if (tid == 0) { invg[r] = 0.f; invu[r] = 0.f; }
    return;
  }
  int e = rows_expert[r];
  const float* wg = (e < NE) ? ng + (size_t)e * HD : sng;
  const float* wu = (e < NE) ? nu + (size_t)e * HD : snu;
  __shared__ float red[3][4];
  float xv[3]; float ss = 0.f;
#pragma unroll
  for (int i = 0; i < 3; ++i) {
    float v = x[(size_t)tok * HD + tid + i * 256];
    v = clipf(v, -100.f, 100.f);
    xv[i] = v; ss += v * v;
  }
  ss = wred_sum(ss);
  if (ln == 0) red[0][wv] = ss;
  __syncthreads();
  float var = fmaxf((red[0][0] + red[0][1] + red[0][2] + red[0][3]) / (float)HD, 1e-5f);
  float rinv = rsqrtf(var + 1e-5f);
  // gate path
  float xng[3], xnu[3]; float ag = 0.f, au = 0.f;
#pragma unroll
  for (int i = 0; i < 3; ++i) {
    float base = clipf(xv[i] * rinv, -10.f, 10.f);
    float tg = clipf(base * wg[tid + i * 256], -50.f, 50.f);
    float tu = clipf(base * wu[tid + i * 256], -50.f, 50.f);
    xng[i] = tg; ag = fmaxf(ag, fabsf(tg));
    xnu[i] = tu; au = fmaxf(au, fabsf(tu));
  }
  ag = wred_max(ag); au = wred_max(au);
  if (ln == 0) { red[1][wv] = ag; red[2][wv] = au; }
  __syncthreads();
  float mg = fmaxf(fmaxf(fmaxf(red[1][0], red[1][1]), fmaxf(red[1][2], red[1][3])), 1e-4f);
  float mu = fmaxf(fmaxf(fmaxf(red[2][0], red[2][1]), fmaxf(red[2][2], red[2][3])), 1e-4f);
  float scg = 127.f / mg, scu = 127.f / mu;
#pragma unroll
  for (int i = 0; i < 3; ++i) {
    xqg[(size_t)r * HD + tid + i * 256] = (signed char)(int)clipf(rintf(xng[i] * scg), -128.f, 127.f);
    xqu[(size_t)r * HD + tid + i * 256] = (signed char)(int)clipf(rintf(xnu[i] * scu), -128.f, 127.f);
  }
  if (tid == 0) { invg[r] = 1.f / scg; invu[r] = 1.f / scu; }
}

// ---------------- fused gate+up int8 GEMM -> hidden (bf16) ----------------
// 512-thread blocks: same 128x128 tile, 8 waves (wave tile 64x32) -> acc is
// 64 AGPR/wave instead of 128, target <=128 total regs so 2 blocks (16
// waves)/CU fit vs round-3's 8 waves. Epilogue silu via __expf + v_rcp.
__global__ __launch_bounds__(512, 4)
void k_gemm_gu(const signed char* __restrict__ xqg, const signed char* __restrict__ xqu,
               const signed char* __restrict__ tw, const float* __restrict__ wscale,
               const float* __restrict__ invg, const float* __restrict__ invu,
               const int* __restrict__ rows_expert, const int* __restrict__ offs,
               __hip_bfloat16* __restrict__ hidden) {
  int n0 = blockIdx.x * BM;
  int row0 = blockIdx.y * BM;
  if (row0 >= offs[NE]) return;
  int e = rows_expert[row0];
  int mg = (e < NE) ? e : 24;
  int mu = (e < NE) ? e + 8 : 25;
  const signed char* wgp = tw + (size_t)mg * MSIZE;
  const signed char* wup = tw + (size_t)mu * MSIZE;
  __shared__ __align__(16) signed char Ag[2 * BM * BK];
  __shared__ __align__(16) signed char Au[2 * BM * BK];
  __shared__ __align__(16) signed char Bg[2 * BM * BK];
  __shared__ __align__(16) signed char Bu[2 * BM * BK];
  __shared__ float sg[BM], su[BM];
  int tid = threadIdx.x, wv = tid >> 6, ln = tid & 63;
  if (tid < BM) { sg[tid] = invg[row0 + tid]; su[tid] = invu[row0 + tid]; }
  v4i accg[4][2] = {};
  v4i accu[4][2] = {};
  // staging: thread tid covers tile row tid>>2, 16B slot tid&3 (LDS offset tid*16)
  int srow = tid >> 2;
  int swz = (((tid & 3) ^ ((srow >> 1) & 3)) << 4);
  const signed char* pag = xqg + (size_t)(row0 + srow) * HD + swz;
  const signed char* pau = xqu + (size_t)(row0 + srow) * HD + swz;
  const signed char* pbg = wgp + (size_t)(n0 + srow) * HD + swz;
  const signed char* pbu = wup + (size_t)(n0 + srow) * HD + swz;
  int cob = wv * 1024;  // wave-uniform LDS chunk base
  // fragment offsets
  int wm = (wv & 1) * 64, wn = (wv >> 1) * 32;
  int fm = ln & 15;
  int slot16 = (((ln >> 4) ^ ((fm >> 1) & 3)) << 4);
  int offA[4], offB[2];
#pragma unroll
  for (int i = 0; i < 4; ++i) offA[i] = (wm + i * 16 + fm) * BK + slot16;
#pragma unroll
  for (int j = 0; j < 2; ++j) offB[j] = (wn + j * 16 + fm) * BK + slot16;

  auto stage = [&](int buf) {
    int co = buf * 8192 + cob;
    g2lds16(pag, &Ag[co]);
    g2lds16(pau, &Au[co]);
    g2lds16(pbg, &Bg[co]);
    g2lds16(pbu, &Bu[co]);
    pag += BK; pau += BK; pbg += BK; pbu += BK;
  };
  auto compute = [&](int buf) {
    int lb = buf * 8192;
    v4i ar[4], ur[4];
#pragma unroll
    for (int i = 0; i < 4; ++i) {
      ar[i] = *(const v4i*)&Ag[lb + offA[i]];
      ur[i] = *(const v4i*)&Au[lb + offA[i]];
    }
#pragma unroll
    for (int j = 0; j < 2; ++j) {
      v4i bg = *(const v4i*)&Bg[lb + offB[j]];
      v4i bu = *(const v4i*)&Bu[lb + offB[j]];
#pragma unroll
      for (int i = 0; i < 4; ++i) {
        accg[i][j] = __builtin_amdgcn_mfma_i32_16x16x64_i8(ar[i], bg, accg[i][j], 0, 0, 0);
        accu[i][j] = __builtin_amdgcn_mfma_i32_16x16x64_i8(ur[i], bu, accu[i][j], 0, 0, 0);
      }
    }
  };

  const int NIT = HD / BK;  // 12
  stage(0);
#pragma unroll 1
  for (int it = 0; it < NIT; it += 2) {
    __syncthreads();
    if (it + 1 < NIT) stage(1);
    compute(0);
    __syncthreads();
    if (it + 2 < NIT) stage(0);
    compute(1);
  }

  float gs = wscale[mg], us = wscale[mu];
  int dq = (ln >> 4) * 4, dn = ln & 15;
#pragma unroll
  for (int i = 0; i < 4; ++i) {
#pragma unroll
    for (int rg = 0; rg < 4; ++rg) {
      int lrow = wm + i * 16 + dq + rg;
      int grow = row0 + lrow;
      float ig = gs * sg[lrow];
      float iu = us * su[lrow];
#pragma unroll
      for (int j = 0; j < 2; ++j) {
        int gcol = n0 + wn + j * 16 + dn;
        float g = (float)accg[i][j][rg] * ig;
        g = clipf(g, -20.f, 20.f);
        float sil = g * __builtin_amdgcn_rcpf(1.f + __expf(-g));
        float u = (float)accu[i][j][rg] * iu;
        float h = clipf(sil * u, -1000.f, 1000.f);
        hidden[(size_t)grow * ID + gcol] = __float2bfloat16(h);
      }
    }
  }
}

// ---------------- hidden quant (vectorized bf16x2 loads, packed i8 stores) --
__global__ __launch_bounds__(256)
void k_hquant(const __hip_bfloat16* __restrict__ hidden, const int* __restrict__ rows_token,
              const int* __restrict__ rows_expert, const float* __restrict__ nd,
              const float* __restrict__ snd, signed char* __restrict__ hq,
              float* __restrict__ invh) {
  int r = blockIdx.x, tid = threadIdx.x;
  int wv = tid >> 6, ln = tid & 63;
  int tok = rows_token[r];
  if (tok < 0) {
    ((unsigned long long*)(hq + (size_t)r * ID))[tid] = 0ull;
    if (tid == 0) invh[r] = 0.f;
    return;
  }
  int e = rows_expert[r];
  const float2* wn2 = (const float2*)((e < NE) ? nd + (size_t)e * ID : snd);
  const unsigned int* h2 = (const unsigned int*)(hidden + (size_t)r * ID);
  __shared__ float red[2][4];
  float xa[4], xb[4]; float ss = 0.f;
#pragma unroll
  for (int i = 0; i < 4; ++i) {
    unsigned int u = h2[tid + i * 256];
    float a = __uint_as_float(u << 16);
    float b = __uint_as_float(u & 0xffff0000u);
    a = clipf(a, -100.f, 100.f); b = clipf(b, -100.f, 100.f);
    xa[i] = a; xb[i] = b; ss += a * a + b * b;
  }
  ss = wred_sum(ss);
  if (ln == 0) red[0][wv] = ss;
  __syncthreads();
  float var = fmaxf((red[0][0] + red[0][1] + red[0][2] + red[0][3]) / (float)ID, 1e-5f);
  float rinv = rsqrtf(var + 1e-5f);
  float na[4], nb[4]; float amax = 0.f;
#pragma unroll
  for (int i = 0; i < 4; ++i) {
    float2 w = wn2[tid + i * 256];
    float ta = clipf(clipf(xa[i] * rinv, -10.f, 10.f) * w.x, -50.f, 50.f);
    float tb = clipf(clipf(xb[i] * rinv, -10.f, 10.f) * w.y, -50.f, 50.f);
    na[i] = ta; nb[i] = tb;
    amax = fmaxf(amax, fmaxf(fabsf(ta), fabsf(tb)));
  }
  amax = wred_max(amax);
  if (ln == 0) red[1][wv] = amax;
  __syncthreads();
  float mx = fmaxf(fmaxf(fmaxf(red[1][0], red[1][1]), fmaxf(red[1][2], red[1][3])), 1e-4f);
  float sc = 127.f / mx;
  unsigned short* hqs = (unsigned short*)(hq + (size_t)r * ID);
#pragma unroll
  for (int i = 0; i < 4; ++i) {
    int qa = (int)clipf(rintf(na[i] * sc), -128.f, 127.f);
    int qb = (int)clipf(rintf(nb[i] * sc), -128.f, 127.f);
    hqs[tid + i * 256] = (unsigned short)((qa & 255) | ((qb & 255) << 8));
  }
  if (tid == 0) invh[r] = 1.f / sc;
}

// ---------------- down int8 GEMM -> y (512 threads, plain stores) ----------
__global__ __launch_bounds__(512, 4)
void k_gemm_down(const signed char* __restrict__ hq, const signed char* __restrict__ tw,
                 const float* __restrict__ wscale, const float* __restrict__ invh,
                 const float* __restrict__ rows_w, const int* __restrict__ rows_expert,
                 const int* __restrict__ offs, float* __restrict__ y) {
  int n0 = blockIdx.x * BM;
  int row0 = blockIdx.y * BM;
  if (row0 >= offs[NE]) return;
  int e = rows_expert[row0];
  int md = (e < NE) ? 16 + e : 26;
  const signed char* wdp = tw + (size_t)md * MSIZE;
  __shared__ __align__(16) signed char As[2 * BM * BK];
  __shared__ __align__(16) signed char Bs[2 * BM * BK];
  __shared__ float s_f[BM];
  int tid = threadIdx.x, wv = tid >> 6, ln = tid & 63;
  if (tid < BM) s_f[tid] = invh[row0 + tid] * rows_w[row0 + tid];
  v4i acc[4][2] = {};
  int srow = tid >> 2;
  int swz = (((tid & 3) ^ ((srow >> 1) & 3)) << 4);
  const signed char* pa = hq + (size_t)(row0 + srow) * ID + swz;
  const signed char* pb = wdp + (size_t)(n0 + srow) * ID + swz;
  int cob = wv * 1024;
  int wm = (wv & 1) * 64, wn = (wv >> 1) * 32;
  int fm = ln & 15;
  int slot16 = (((ln >> 4) ^ ((fm >> 1) & 3)) << 4);
  int offA[4], offB[2];
#pragma unroll
  for (int i = 0; i < 4; ++i) offA[i] = (wm + i * 16 + fm) * BK + slot16;
#pragma unroll
  for (int j = 0; j < 2; ++j) offB[j] = (wn + j * 16 + fm) * BK + slot16;

  auto stage = [&](int buf) {
    int co = buf * 8192 + cob;
    g2lds16(pa, &As[co]);
    g2lds16(pb, &Bs[co]);
    pa += BK; pb += BK;
  };
  auto compute = [&](int buf) {
    int lb = buf * 8192;
    v4i a[4];
#pragma unroll
    for (int i = 0; i < 4; ++i) a[i] = *(const v4i*)&As[lb + offA[i]];
#pragma unroll
    for (int j = 0; j < 2; ++j) {
      v4i b = *(const v4i*)&Bs[lb + offB[j]];
#pragma unroll
      for (int i = 0; i < 4; ++i)
        acc[i][j] = __builtin_amdgcn_mfma_i32_16x16x64_i8(a[i], b, acc[i][j], 0, 0, 0);
    }
  };

  const int NIT = ID / BK;  // 32
  stage(0);
#pragma unroll 1
  for (int it = 0; it < NIT; it += 2) {
    __syncthreads();
    if (it + 1 < NIT) stage(1);
    compute(0);
    __syncthreads();
    if (it + 2 < NIT) stage(0);
    compute(1);
  }

  float ds = wscale[md];
  int dq = (ln >> 4) * 4, dn = ln & 15;
#pragma unroll
  for (int i = 0; i < 4; ++i) {
#pragma unroll
    for (int rg = 0; rg < 4; ++rg) {
      int lrow = wm + i * 16 + dq + rg;
      float f = ds * s_f[lrow];
#pragma unroll
      for (int j = 0; j < 2; ++j) {
        int gcol = n0 + wn + j * 16 + dn;
        y[(size_t)(row0 + lrow) * HD + gcol] = (float)acc[i][j][rg] * f;
      }
    }
  }
}

// ---------------- final gather: out[t] = clip(y[t] + y[r1] + y[r2]) ---------
__global__ __launch_bounds__(192)
void k_gather(const float* __restrict__ y, const int* __restrict__ inv_row,
              float* __restrict__ out) {
  int t = blockIdx.x, c = threadIdx.x;
  int r1 = inv_row[t * 2 + 0], r2 = inv_row[t * 2 + 1];
  const float4* y4 = (const float4*)y;
  float4 a = y4[(size_t)t * 192 + c];
  float4 b = y4[(size_t)r1 * 192 + c];
  float4 d = y4[(size_t)r2 * 192 + c];
  float4 o;
  o.x = clipf(a.x + b.x + d.x, -10000.f, 10000.f);
  o.y = clipf(a.y + b.y + d.y, -10000.f, 10000.f);
  o.z = clipf(a.z + b.z + d.z, -10000.f, 10000.f);
  o.w = clipf(a.w + b.w + d.w, -10000.f, 10000.f);
  ((float4*)out)[(size_t)t * 192 + c] = o;
}

// ---------------- host launcher ----------------
extern "C" void kernel_launch(void* const* d_in, const int* in_sizes, int n_in,
                              void* d_out, int out_size, void* d_ws, size_t ws_size,
                              hipStream_t stream) {
  (void)in_sizes; (void)n_in; (void)out_size; (void)ws_size;
  const float* x   = (const float*)d_in[0];
  const float* rw  = (const float*)d_in[1];
  const float* rb  = (const float*)d_in[2];
  const float* Wg  = (const float*)d_in[3];
  const float* Wu  = (const float*)d_in[4];
  const float* Wd  = (const float*)d_in[5];
  const float* ng  = (const float*)d_in[6];
  const float* nu  = (const float*)d_in[7];
  const float* nd  = (const float*)d_in[8];
  const float* sWg = (const float*)d_in[9];
  const float* sWu = (const float*)d_in[10];
  const float* sWd = (const float*)d_in[11];
  const float* sng = (const float*)d_in[12];
  const float* snu = (const float*)d_in[13];
  const float* snd = (const float*)d_in[14];
  float* out = (float*)d_out;
  float* logits = out + (size_t)TOK * HD;

  char* ws = (char*)d_ws;
  size_t off = 0;
  auto alloc = [&](size_t b) { size_t o = off; off = (off + b + 255) & ~(size_t)255; return o; };
  signed char* tw   = (signed char*)(ws + alloc((size_t)27 * MSIZE));
  double* stats     = (double*)(ws + alloc(27 * 2 * sizeof(double)));
  double* wmean     = (double*)(ws + alloc(27 * sizeof(double)));
  float* wscale     = (float*)(ws + alloc(27 * sizeof(float)));
  int* counts       = (int*)(ws + alloc(8 * sizeof(int)));
  int* fill         = (int*)(ws + alloc(8 * sizeof(int)));
  int* offs         = (int*)(ws + alloc(16 * sizeof(int)));
  int* top_idx      = (int*)(ws + alloc((size_t)TOK * 2 * sizeof(int)));
  float* top_w      = (float*)(ws + alloc((size_t)TOK * 2 * sizeof(float)));
  int* inv_row      = (int*)(ws + alloc((size_t)TOK * 2 * sizeof(int)));
  int* rows_token   = (int*)(ws + alloc((size_t)R_MAX * sizeof(int)));
  float* rows_w     = (float*)(ws + alloc((size_t)R_MAX * sizeof(float)));
  int* rows_expert  = (int*)(ws + alloc((size_t)R_MAX * sizeof(int)));
  float* invg       = (float*)(ws + alloc((size_t)R_MAX * sizeof(float)));
  float* invu       = (float*)(ws + alloc((size_t)R_MAX * sizeof(float)));
  float* invh       = (float*)(ws + alloc((size_t)R_MAX * sizeof(float)));
  // hq region; xqg/xqu alias its front (safe: xq consumed by k_gemm_gu before k_hquant writes hq)
  signed char* hq   = (signed char*)(ws + alloc((size_t)R_MAX * ID));
  signed char* xqg  = hq;
  signed char* xqu  = hq + (size_t)R_MAX * HD;
  // hidden region; y (fp32 down-GEMM output, R_MAX*HD*4 = 78 MB) aliases it —
  // hidden (105 MB) is dead after k_hquant, before k_gemm_down writes y.
  char* hid_region  = ws + alloc((size_t)R_MAX * ID * 2);
  __hip_bfloat16* hidden = (__hip_bfloat16*)hid_region;
  float* y          = (float*)hid_region;

  hipMemsetAsync(stats, 0, 27 * 2 * sizeof(double), stream);

  k_wstats<<<dim3(64, 27), 256, 0, stream>>>(Wg, Wu, Wd, sWg, sWu, sWd, stats);
  k_wfinal<<<1, 32, 0, stream>>>(stats, wmean, wscale);
  k_wquant<<<dim3(256, 27), 256, 0, stream>>>(Wg, Wu, Wd, sWg, sWu, sWd, wmean, tw);
  k_router<<<TOK / 4, 256, 0, stream>>>(x, rw, rb, logits, top_idx, top_w);
  k_hist<<<1, 1024, 0, stream>>>(top_idx, counts);
  k_initrows<<<(R_MAX + 255) / 256, 256, 0, stream>>>(rows_token, rows_w, rows_expert);
  k_offsets<<<1, 64, 0, stream>>>(counts, offs, fill);
  k_scatter<<<TOK / 256, 256, 0, stream>>>(top_idx, top_w, offs, fill, rows_token,
                                           rows_w, rows_expert, inv_row);
  k_actquant<<<R_MAX, 256, 0, stream>>>(x, rows_token, rows_expert, ng, nu, sng, snu,
                                        xqg, xqu, invg, invu);
  k_gemm_gu<<<dim3(ID / BM, R_MAX / BM), 512, 0, stream>>>(xqg, xqu, tw, wscale, invg, invu,
                                                           rows_expert, offs, hidden);
  k_hquant<<<R_MAX, 256, 0, stream>>>(hidden, rows_token, rows_expert, nd, snd, hq, invh);
  k_gemm_down<<<dim3(HD / BM, R_MAX / BM), 512, 0, stream>>>(hq, tw, wscale, invh,
                                                             rows_w, rows_expert, offs, y);
  k_gather<<<TOK, 192, 0, stream>>>(y, inv_row, out);
}